// Round 1
// baseline (841.193 us; speedup 1.0000x reference)
//
#include <hip/hip_runtime.h>

// MHA: B=4 S=2048 D=1024 H=16 DH=64. Full bf16-MFMA pipeline (fp32 accum).

#define Bn  4
#define Sn  2048
#define Dn  1024
#define Hn  16
#define DHn 64
#define Mn  (Bn*Sn)          // 8192 rows

typedef unsigned short u16;
typedef __attribute__((ext_vector_type(8))) short short8;   // 8 x bf16 (4 VGPRs)
typedef __attribute__((ext_vector_type(4))) short short4v;  // 4 x bf16 (2 VGPRs)
typedef __attribute__((ext_vector_type(4))) float f32x4;    // MFMA C/D frag
typedef __attribute__((ext_vector_type(2))) unsigned int uint2v;

__device__ __forceinline__ u16 f2bf(float f) {
  unsigned u = __float_as_uint(f);
  return (u16)((u + 0x7FFFu + ((u >> 16) & 1u)) >> 16);   // RNE
}

// async 16B/lane global->LDS DMA; lds dest = wave-uniform base + lane*16
__device__ __forceinline__ void async16(const void* g, void* l) {
  __builtin_amdgcn_global_load_lds(
      (const __attribute__((address_space(1))) void*)g,
      (__attribute__((address_space(3))) void*)l, 16, 0, 0);
}

// pack 2 fp32 -> 2 bf16 (truncation) in one v_perm_b32
__device__ __forceinline__ unsigned pk2(float a, float b) {
  return __builtin_amdgcn_perm(__float_as_uint(b), __float_as_uint(a), 0x07060302u);
}

// ---------------- convert: x (f32) -> xb (bf16) ----------------
__global__ __launch_bounds__(256) void k_convert_x(
    const float4* __restrict__ x, ushort4* __restrict__ xb, int n4) {
  int i = blockIdx.x * 256 + threadIdx.x;
  if (i < n4) {
    float4 f = x[i];
    ushort4 o;
    o.x = f2bf(f.x); o.y = f2bf(f.y); o.z = f2bf(f.z); o.w = f2bf(f.w);
    xb[i] = o;
  }
}

// ---- convert+transpose weights to [N][K] bf16 via LDS 64x64 tiles ----
__global__ __launch_bounds__(256) void k_convert_w(
    const float* __restrict__ Wq, const float* __restrict__ Wk,
    const float* __restrict__ Wv, const float* __restrict__ Wo,
    u16* __restrict__ WqT, u16* __restrict__ WkT,
    u16* __restrict__ WvT, u16* __restrict__ WoT) {
  __shared__ float t[64][65];
  const int bid = blockIdx.x;          // 0..1023
  const int wsel = bid >> 8;           // 0..3
  const int idx = bid & 255;
  const int tid = threadIdx.x;
  const int c = tid & 63;
  const int r4 = tid >> 6;             // 0..3

  if (wsel < 3) {
    const float* W = (wsel == 0) ? Wq : (wsel == 1) ? Wk : Wv;
    u16* T = (wsel == 0) ? WqT : (wsel == 1) ? WkT : WvT;
    const int h = idx >> 4;
    const int d0 = (idx & 15) * 64;
    const float* src = W + (size_t)h * (Dn * DHn) + (size_t)d0 * DHn;
#pragma unroll
    for (int r = 0; r < 16; r++) {
      int row = r * 4 + r4;
      t[row][c] = src[row * DHn + c];
    }
    __syncthreads();
    u16* dst = T + (size_t)(h * 64) * Dn + d0;
#pragma unroll
    for (int r = 0; r < 16; r++) {
      int erow = r * 4 + r4;
      dst[(size_t)erow * Dn + c] = f2bf(t[c][erow]);
    }
  } else {
    const int n0 = (idx >> 4) * 64;
    const int d0 = (idx & 15) * 64;
#pragma unroll
    for (int r = 0; r < 16; r++) {
      int row = r * 4 + r4;
      t[row][c] = Wo[(size_t)(d0 + row) * Dn + n0 + c];
    }
    __syncthreads();
#pragma unroll
    for (int r = 0; r < 16; r++) {
      int nrow = r * 4 + r4;
      WoT[(size_t)(n0 + nrow) * Dn + d0 + c] = f2bf(t[c][nrow]);
    }
  }
}

// ---------------- QKV projection GEMM: 512 thr / 8 waves, 128x128 tile ----------------
template<int SWAP>
__global__ __launch_bounds__(512) void k_gemm_qkv(
    const u16* __restrict__ A, const u16* __restrict__ B0T,
    const u16* __restrict__ B1T, const float* __restrict__ bias0,
    const float* __restrict__ bias1, u16* __restrict__ out0,
    u16* __restrict__ out1) {
  const int z = blockIdx.z;
  const u16* BT = z ? B1T : B0T;
  const float* bias = z ? bias1 : bias0;
  u16* dst = z ? out1 : out0;
  const int tile_m = blockIdx.x * 128;
  const int tile_n = blockIdx.y * 128;
  const int K = Dn;

  __shared__ u16 As[128 * 64];
  __shared__ u16 Bs[128 * 64];

  const int tid = threadIdx.x;
  const int lane = tid & 63;
  const int wave = tid >> 6;                    // 0..7
  const int wm = wave & 3, wn = wave >> 2;
  const int quad = lane >> 4, l16 = lane & 15;
  const int srow8 = lane >> 3;
  const int gchunk = (lane & 7) ^ srow8;
  const int sw = l16 & 7;

  f32x4 acc[2][4];
#pragma unroll
  for (int i = 0; i < 2; i++)
#pragma unroll
    for (int j = 0; j < 4; j++) acc[i][j] = (f32x4){0.f, 0.f, 0.f, 0.f};

  for (int k0 = 0; k0 < K; k0 += 64) {
    const int rb = wave * 16;
    async16(&A[(size_t)(tile_m + rb + srow8) * K + k0 + gchunk * 8], &As[rb * 64]);
    async16(&A[(size_t)(tile_m + rb + 8 + srow8) * K + k0 + gchunk * 8], &As[(rb + 8) * 64]);
    async16(&BT[(size_t)(tile_n + rb + srow8) * K + k0 + gchunk * 8], &Bs[rb * 64]);
    async16(&BT[(size_t)(tile_n + rb + 8 + srow8) * K + k0 + gchunk * 8], &Bs[(rb + 8) * 64]);
    __syncthreads();
#pragma unroll
    for (int ks = 0; ks < 2; ++ks) {
      short8 a[2], b[4];
#pragma unroll
      for (int i = 0; i < 2; i++)
        a[i] = *(const short8*)&As[(wm * 32 + i * 16 + l16) * 64 + ((ks * 4 + quad) ^ sw) * 8];
#pragma unroll
      for (int j = 0; j < 4; j++)
        b[j] = *(const short8*)&Bs[(wn * 64 + j * 16 + l16) * 64 + ((ks * 4 + quad) ^ sw) * 8];
#pragma unroll
      for (int i = 0; i < 2; i++)
#pragma unroll
        for (int j = 0; j < 4; j++)
          acc[i][j] = SWAP
              ? __builtin_amdgcn_mfma_f32_16x16x32_bf16(b[j], a[i], acc[i][j], 0, 0, 0)
              : __builtin_amdgcn_mfma_f32_16x16x32_bf16(a[i], b[j], acc[i][j], 0, 0, 0);
    }
    __syncthreads();
  }

  if (SWAP) {
    const float scale = (z == 0) ? 0.18033688011112042f : 1.0f;
#pragma unroll
    for (int i = 0; i < 2; i++) {
      const int s = tile_m + wm * 32 + i * 16 + l16;
      const int bb = s >> 11, sl = s & 2047;
#pragma unroll
      for (int j = 0; j < 4; j++) {
        const int nb = tile_n + wn * 64 + j * 16 + quad * 4;
        const float4 b4 = *(const float4*)&bias[nb];
        const int h = nb >> 6, e0 = nb & 63;
        ushort4 o;
        o.x = f2bf((acc[i][j][0] + b4.x) * scale);
        o.y = f2bf((acc[i][j][1] + b4.y) * scale);
        o.z = f2bf((acc[i][j][2] + b4.z) * scale);
        o.w = f2bf((acc[i][j][3] + b4.w) * scale);
        *(ushort4*)&dst[((size_t)(bb * Hn + h) * Sn + sl) * DHn + e0] = o;
      }
    }
  } else {
#pragma unroll
    for (int i = 0; i < 2; i++) {
      const int s0 = tile_m + wm * 32 + i * 16 + quad * 4;
      const int bb = s0 >> 11, sl = s0 & 2047;
#pragma unroll
      for (int j = 0; j < 4; j++) {
        const int n = tile_n + wn * 64 + j * 16 + l16;
        const int h = n >> 6, e = n & 63;
        const float bn = bias[n];
        ushort4 o;
        o.x = f2bf(acc[i][j][0] + bn);
        o.y = f2bf(acc[i][j][1] + bn);
        o.z = f2bf(acc[i][j][2] + bn);
        o.w = f2bf(acc[i][j][3] + bn);
        *(ushort4*)&dst[((size_t)(bb * Hn + h) * DHn + e) * Sn + sl] = o;
      }
    }
  }
}

// ---------------- flash attention: 512 thr / 8 waves, key-split halves ----------------
// Waves 0-3: q-groups 0-3 x keys 0-31 of each tile; waves 4-7: same q x keys 32-63.
// 4 blocks/CU x 8 waves = 32 waves/CU (was 16). Partials merged via LDS at end.
// K and V both staged by global_load_lds with pre-swizzled source (chunk XOR row&7).
__global__ __launch_bounds__(512, 8) void k_attn(
    const u16* __restrict__ qg, const u16* __restrict__ kg,
    const u16* __restrict__ vg, u16* __restrict__ ctx) {
  const int bh = blockIdx.y;
  const int b = bh >> 4, h = bh & 15;
  const int tid = threadIdx.x;
  const int wave = tid >> 6, lane = tid & 63;
  const int quad = lane >> 4, l16 = lane & 15;
  const int kh = wave >> 2;                 // key half: 0 => keys 0-31, 1 => 32-63
  const int qw = wave & 3;                  // q group
  const int qbase = blockIdx.x * 128 + qw * 32;

  const u16* qp = qg + (size_t)bh * Sn * DHn;
  const u16* kp = kg + (size_t)bh * Sn * DHn;
  const u16* vp = vg + (size_t)bh * DHn * Sn;   // [DH][S]

  __shared__ u16 SM[4][64 * 64];   // [0..1] = K dbuf, [2..3] = V dbuf (32 KB)

  const int srow8 = lane >> 3;
  const int gchunk = (lane & 7) ^ srow8;
  const int sw = l16 & 7;
  const int rbase = wave * 8;               // 8 waves x 8 rows = 64-row tile

  short8 bq[2][2];
#pragma unroll
  for (int g2 = 0; g2 < 2; g2++) {
    bq[g2][0] = *(const short8*)&qp[(size_t)(qbase + g2 * 16 + l16) * DHn + quad * 8];
    bq[g2][1] = *(const short8*)&qp[(size_t)(qbase + g2 * 16 + l16) * DHn + 32 + quad * 8];
  }

  f32x4 octx[2][4];
#pragma unroll
  for (int g2 = 0; g2 < 2; g2++)
#pragma unroll
    for (int j = 0; j < 4; j++) octx[g2][j] = (f32x4){0.f, 0.f, 0.f, 0.f};
  float lr[2] = {0.f, 0.f};

  // prologue: stage tile 0 (each wave stages 8 rows of K and 8 rows of V)
  async16(&kp[(size_t)(rbase + srow8) * DHn + gchunk * 8], &SM[0][rbase * 64]);
  async16(&vp[(size_t)(rbase + srow8) * Sn + gchunk * 8], &SM[2][rbase * 64]);
  __syncthreads();

  for (int kt = 0; kt < Sn / 64; ++kt) {
    const int cur = kt & 1, nxt = cur ^ 1;
    if (kt + 1 < Sn / 64) {
      const int key1 = (kt + 1) * 64;
      async16(&kp[(size_t)(key1 + rbase + srow8) * DHn + gchunk * 8], &SM[nxt][rbase * 64]);
      async16(&vp[(size_t)(rbase + srow8) * Sn + key1 + gchunk * 8], &SM[2 + nxt][rbase * 64]);
    }

    short4v ap[2][2];
#pragma unroll
    for (int g = 0; g < 2; g++) {
      const int krow = kh * 32 + g * 16 + l16;
      short8 ka0 = *(const short8*)&SM[cur][krow * 64 + (quad ^ sw) * 8];
      short8 ka1 = *(const short8*)&SM[cur][krow * 64 + ((quad + 4) ^ sw) * 8];
#pragma unroll
      for (int g2 = 0; g2 < 2; g2++) {
        f32x4 sc = (f32x4){0.f, 0.f, 0.f, 0.f};
        __builtin_amdgcn_s_setprio(1);
        sc = __builtin_amdgcn_mfma_f32_16x16x32_bf16(ka0, bq[g2][0], sc, 0, 0, 0);
        sc = __builtin_amdgcn_mfma_f32_16x16x32_bf16(ka1, bq[g2][1], sc, 0, 0, 0);
        __builtin_amdgcn_s_setprio(0);
        float p[4];
#pragma unroll
        for (int r = 0; r < 4; r++) p[r] = __builtin_amdgcn_exp2f(sc[r]);
        lr[g2] += (p[0] + p[1]) + (p[2] + p[3]);
        ap[g2][g] = __builtin_bit_cast(short4v,
            (uint2v){pk2(p[0], p[1]), pk2(p[2], p[3])});
      }
    }

    __builtin_amdgcn_s_setprio(1);
#pragma unroll
    for (int j = 0; j < 4; j++) {
#pragma unroll
      for (int g = 0; g < 2; g++) {
        short4v vb = *(const short4v*)&SM[2 + cur][(j * 16 + l16) * 64 +
            (((kh * 4 + g * 2 + (quad >> 1)) ^ sw) * 8) + (quad & 1) * 4];
        octx[0][j] = __builtin_amdgcn_mfma_f32_16x16x16bf16_1k(ap[0][g], vb, octx[0][j], 0, 0, 0);
        octx[1][j] = __builtin_amdgcn_mfma_f32_16x16x16bf16_1k(ap[1][g], vb, octx[1][j], 0, 0, 0);
      }
    }
    __builtin_amdgcn_s_setprio(0);
    __syncthreads();
  }

  // ---- merge key-half partials (waves kh=1 -> kh=0) via LDS, 2 phases ----
  float* mbuf = (float*)&SM[0][0];         // 16 KB octx slab
  float* lrbuf = mbuf + 4096;              // +1 KB lr slab
#pragma unroll
  for (int g2 = 0; g2 < 2; g2++) {
    __syncthreads();
    if (kh == 1) {
#pragma unroll
      for (int j = 0; j < 4; j++)
        *(f32x4*)&mbuf[((qw * 4 + j) * 64 + lane) * 4] = octx[g2][j];
      lrbuf[qw * 64 + lane] = lr[g2];
    }
    __syncthreads();
    if (kh == 0) {
#pragma unroll
      for (int j = 0; j < 4; j++) {
        f32x4 o = *(const f32x4*)&mbuf[((qw * 4 + j) * 64 + lane) * 4];
        octx[g2][j][0] += o[0]; octx[g2][j][1] += o[1];
        octx[g2][j][2] += o[2]; octx[g2][j][3] += o[3];
      }
      lr[g2] += lrbuf[qw * 64 + lane];
    }
  }
  if (kh) return;

#pragma unroll
  for (int g2 = 0; g2 < 2; g2++) {
    lr[g2] += __shfl_xor(lr[g2], 16, 64);
    lr[g2] += __shfl_xor(lr[g2], 32, 64);
  }
  float rl[2][4];
#pragma unroll
  for (int g2 = 0; g2 < 2; g2++)
#pragma unroll
    for (int r = 0; r < 4; r++)
      rl[g2][r] = 1.0f / __shfl(lr[g2], quad * 4 + r, 64);

#pragma unroll
  for (int g2 = 0; g2 < 2; g2++)
#pragma unroll
    for (int j = 0; j < 4; j++) {
      const int n = h * DHn + j * 16 + l16;
#pragma unroll
      for (int r = 0; r < 4; r++) {
        const int s = qbase + g2 * 16 + quad * 4 + r;
        ctx[(size_t)(b * Sn + s) * Dn + n] = f2bf(octx[g2][j][r] * rl[g2][r]);
      }
    }
}

// ---------------- output projection GEMM: 512 thr / 8 waves, swapped epilogue ----------------
__global__ __launch_bounds__(512) void k_gemm_out(
    const u16* __restrict__ A, const u16* __restrict__ WoT,
    const float* __restrict__ bo, float* __restrict__ out) {
  const int tile_m = blockIdx.x * 128;
  const int tile_n = blockIdx.y * 128;
  const int K = Dn;

  __shared__ u16 As[128 * 64];
  __shared__ u16 Bs[128 * 64];

  const int tid = threadIdx.x;
  const int lane = tid & 63;
  const int wave = tid >> 6;
  const int wm = wave & 3, wn = wave >> 2;
  const int quad = lane >> 4, l16 = lane & 15;
  const int srow8 = lane >> 3;
  const int gchunk = (lane & 7) ^ srow8;
  const int sw = l16 & 7;

  f32x4 acc[2][4];
#pragma unroll
  for (int i = 0; i < 2; i++)
#pragma unroll
    for (int j = 0; j < 4; j++) acc[i][j] = (f32x4){0.f, 0.f, 0.f, 0.f};

  for (int k0 = 0; k0 < K; k0 += 64) {
    const int rb = wave * 16;
    async16(&A[(size_t)(tile_m + rb + srow8) * K + k0 + gchunk * 8], &As[rb * 64]);
    async16(&A[(size_t)(tile_m + rb + 8 + srow8) * K + k0 + gchunk * 8], &As[(rb + 8) * 64]);
    async16(&WoT[(size_t)(tile_n + rb + srow8) * K + k0 + gchunk * 8], &Bs[rb * 64]);
    async16(&WoT[(size_t)(tile_n + rb + 8 + srow8) * K + k0 + gchunk * 8], &Bs[(rb + 8) * 64]);
    __syncthreads();
#pragma unroll
    for (int ks = 0; ks < 2; ++ks) {
      short8 a[2], b[4];
#pragma unroll
      for (int i = 0; i < 2; i++)
        a[i] = *(const short8*)&As[(wm * 32 + i * 16 + l16) * 64 + ((ks * 4 + quad) ^ sw) * 8];
#pragma unroll
      for (int j = 0; j < 4; j++)
        b[j] = *(const short8*)&Bs[(wn * 64 + j * 16 + l16) * 64 + ((ks * 4 + quad) ^ sw) * 8];
#pragma unroll
      for (int i = 0; i < 2; i++)
#pragma unroll
        for (int j = 0; j < 4; j++)
          acc[i][j] = __builtin_amdgcn_mfma_f32_16x16x32_bf16(b[j], a[i], acc[i][j], 0, 0, 0);
    }
    __syncthreads();
  }

#pragma unroll
  for (int i = 0; i < 2; i++) {
    const int s = tile_m + wm * 32 + i * 16 + l16;
#pragma unroll
    for (int j = 0; j < 4; j++) {
      const int nb = tile_n + wn * 64 + j * 16 + quad * 4;
      const float4 b4 = *(const float4*)&bo[nb];
      float4 o;
      o.x = acc[i][j][0] + b4.x;
      o.y = acc[i][j][1] + b4.y;
      o.z = acc[i][j][2] + b4.z;
      o.w = acc[i][j][3] + b4.w;
      *(float4*)&out[(size_t)s * Dn + nb] = o;
    }
  }
}

extern "C" void kernel_launch(void* const* d_in, const int* in_sizes, int n_in,
                              void* d_out, int out_size, void* d_ws, size_t ws_size,
                              hipStream_t stream) {
  const float* x  = (const float*)d_in[0];
  const float* Wq = (const float*)d_in[1];
  const float* bq = (const float*)d_in[2];
  const float* Wk = (const float*)d_in[3];
  const float* bk = (const float*)d_in[4];
  const float* Wv = (const float*)d_in[5];
  const float* bv = (const float*)d_in[6];
  const float* Wo = (const float*)d_in[7];
  const float* bo = (const float*)d_in[8];
  float* out = (float*)d_out;

  // workspace carve-up (ctx aliases xb: xb dead after k_gemm_qkv) — ~75.5 MB
  char* ws = (char*)d_ws;
  u16* xb  = (u16*)ws;  ws += (size_t)Mn * Dn * 2;
  u16* WqT = (u16*)ws;  ws += (size_t)Dn * Dn * 2;
  u16* WkT = (u16*)ws;  ws += (size_t)Dn * Dn * 2;
  u16* WvT = (u16*)ws;  ws += (size_t)Dn * Dn * 2;
  u16* WoT = (u16*)ws;  ws += (size_t)Dn * Dn * 2;
  u16* qb  = (u16*)ws;  ws += (size_t)Mn * Dn * 2;
  u16* kb  = (u16*)ws;  ws += (size_t)Mn * Dn * 2;
  u16* vtb = (u16*)ws;  ws += (size_t)Mn * Dn * 2;
  u16* ctx = xb;        // alias

  k_convert_x<<<(Mn * Dn / 4) / 256, 256, 0, stream>>>((const float4*)x, (ushort4*)xb, Mn * Dn / 4);
  k_convert_w<<<1024, 256, 0, stream>>>(Wq, Wk, Wv, Wo, WqT, WkT, WvT, WoT);

  dim3 g1(Mn / 128, Dn / 128, 2);
  k_gemm_qkv<1><<<g1, 512, 0, stream>>>(xb, WqT, WkT, bq, bk, qb, kb);
  dim3 g1v(Mn / 128, Dn / 128, 1);
  k_gemm_qkv<0><<<g1v, 512, 0, stream>>>(xb, WvT, nullptr, bv, nullptr, vtb, nullptr);

  dim3 g2(Sn / 128, Bn * Hn);
  k_attn<<<g2, 512, 0, stream>>>(qb, kb, vtb, ctx);

  dim3 g3(Mn / 128, Dn / 128);
  k_gemm_out<<<g3, 512, 0, stream>>>(ctx, WoT, bo, out);
}

// Round 2
// 308.635 us; speedup vs baseline: 2.7255x; 2.7255x over previous
//
#include <hip/hip_runtime.h>

// MHA: B=4 S=2048 D=1024 H=16 DH=64. Full bf16-MFMA pipeline (fp32 accum).

#define Bn  4
#define Sn  2048
#define Dn  1024
#define Hn  16
#define DHn 64
#define Mn  (Bn*Sn)          // 8192 rows
#define LDKV 72              // attn V LDS row stride (ushorts)

typedef unsigned short u16;
typedef __attribute__((ext_vector_type(8))) short short8;   // 8 x bf16 (4 VGPRs)
typedef __attribute__((ext_vector_type(4))) short short4v;  // 4 x bf16 (2 VGPRs)
typedef __attribute__((ext_vector_type(4))) float f32x4;    // MFMA C/D frag
typedef __attribute__((ext_vector_type(2))) unsigned int uint2v;

__device__ __forceinline__ u16 f2bf(float f) {
  unsigned u = __float_as_uint(f);
  return (u16)((u + 0x7FFFu + ((u >> 16) & 1u)) >> 16);   // RNE
}

// async 16B/lane global->LDS DMA; lds dest = wave-uniform base + lane*16
__device__ __forceinline__ void async16(const void* g, void* l) {
  __builtin_amdgcn_global_load_lds(
      (const __attribute__((address_space(1))) void*)g,
      (__attribute__((address_space(3))) void*)l, 16, 0, 0);
}

// pack 2 fp32 -> 2 bf16 (truncation) in one v_perm_b32
__device__ __forceinline__ unsigned pk2(float a, float b) {
  return __builtin_amdgcn_perm(__float_as_uint(b), __float_as_uint(a), 0x07060302u);
}

// ---------------- convert: x (f32) -> xb (bf16) ----------------
__global__ __launch_bounds__(256) void k_convert_x(
    const float4* __restrict__ x, ushort4* __restrict__ xb, int n4) {
  int i = blockIdx.x * 256 + threadIdx.x;
  if (i < n4) {
    float4 f = x[i];
    ushort4 o;
    o.x = f2bf(f.x); o.y = f2bf(f.y); o.z = f2bf(f.z); o.w = f2bf(f.w);
    xb[i] = o;
  }
}

// ---- convert+transpose weights to [N][K] bf16 via LDS 64x64 tiles ----
__global__ __launch_bounds__(256) void k_convert_w(
    const float* __restrict__ Wq, const float* __restrict__ Wk,
    const float* __restrict__ Wv, const float* __restrict__ Wo,
    u16* __restrict__ WqT, u16* __restrict__ WkT,
    u16* __restrict__ WvT, u16* __restrict__ WoT) {
  __shared__ float t[64][65];
  const int bid = blockIdx.x;          // 0..1023
  const int wsel = bid >> 8;           // 0..3
  const int idx = bid & 255;
  const int tid = threadIdx.x;
  const int c = tid & 63;
  const int r4 = tid >> 6;             // 0..3

  if (wsel < 3) {
    const float* W = (wsel == 0) ? Wq : (wsel == 1) ? Wk : Wv;
    u16* T = (wsel == 0) ? WqT : (wsel == 1) ? WkT : WvT;
    const int h = idx >> 4;
    const int d0 = (idx & 15) * 64;
    const float* src = W + (size_t)h * (Dn * DHn) + (size_t)d0 * DHn;
#pragma unroll
    for (int r = 0; r < 16; r++) {
      int row = r * 4 + r4;
      t[row][c] = src[row * DHn + c];
    }
    __syncthreads();
    u16* dst = T + (size_t)(h * 64) * Dn + d0;
#pragma unroll
    for (int r = 0; r < 16; r++) {
      int erow = r * 4 + r4;
      dst[(size_t)erow * Dn + c] = f2bf(t[c][erow]);
    }
  } else {
    const int n0 = (idx >> 4) * 64;
    const int d0 = (idx & 15) * 64;
#pragma unroll
    for (int r = 0; r < 16; r++) {
      int row = r * 4 + r4;
      t[row][c] = Wo[(size_t)(d0 + row) * Dn + n0 + c];
    }
    __syncthreads();
#pragma unroll
    for (int r = 0; r < 16; r++) {
      int nrow = r * 4 + r4;
      WoT[(size_t)(n0 + nrow) * Dn + d0 + c] = f2bf(t[c][nrow]);
    }
  }
}

// ---------------- QKV projection GEMM: 512 thr / 8 waves, 128x128 tile ----------------
template<int SWAP>
__global__ __launch_bounds__(512) void k_gemm_qkv(
    const u16* __restrict__ A, const u16* __restrict__ B0T,
    const u16* __restrict__ B1T, const float* __restrict__ bias0,
    const float* __restrict__ bias1, u16* __restrict__ out0,
    u16* __restrict__ out1) {
  const int z = blockIdx.z;
  const u16* BT = z ? B1T : B0T;
  const float* bias = z ? bias1 : bias0;
  u16* dst = z ? out1 : out0;
  const int tile_m = blockIdx.x * 128;
  const int tile_n = blockIdx.y * 128;
  const int K = Dn;

  __shared__ u16 As[128 * 64];
  __shared__ u16 Bs[128 * 64];

  const int tid = threadIdx.x;
  const int lane = tid & 63;
  const int wave = tid >> 6;                    // 0..7
  const int wm = wave & 3, wn = wave >> 2;
  const int quad = lane >> 4, l16 = lane & 15;
  const int srow8 = lane >> 3;
  const int gchunk = (lane & 7) ^ srow8;
  const int sw = l16 & 7;

  f32x4 acc[2][4];
#pragma unroll
  for (int i = 0; i < 2; i++)
#pragma unroll
    for (int j = 0; j < 4; j++) acc[i][j] = (f32x4){0.f, 0.f, 0.f, 0.f};

  for (int k0 = 0; k0 < K; k0 += 64) {
    const int rb = wave * 16;
    async16(&A[(size_t)(tile_m + rb + srow8) * K + k0 + gchunk * 8], &As[rb * 64]);
    async16(&A[(size_t)(tile_m + rb + 8 + srow8) * K + k0 + gchunk * 8], &As[(rb + 8) * 64]);
    async16(&BT[(size_t)(tile_n + rb + srow8) * K + k0 + gchunk * 8], &Bs[rb * 64]);
    async16(&BT[(size_t)(tile_n + rb + 8 + srow8) * K + k0 + gchunk * 8], &Bs[(rb + 8) * 64]);
    __syncthreads();
#pragma unroll
    for (int ks = 0; ks < 2; ++ks) {
      short8 a[2], b[4];
#pragma unroll
      for (int i = 0; i < 2; i++)
        a[i] = *(const short8*)&As[(wm * 32 + i * 16 + l16) * 64 + ((ks * 4 + quad) ^ sw) * 8];
#pragma unroll
      for (int j = 0; j < 4; j++)
        b[j] = *(const short8*)&Bs[(wn * 64 + j * 16 + l16) * 64 + ((ks * 4 + quad) ^ sw) * 8];
#pragma unroll
      for (int i = 0; i < 2; i++)
#pragma unroll
        for (int j = 0; j < 4; j++)
          acc[i][j] = SWAP
              ? __builtin_amdgcn_mfma_f32_16x16x32_bf16(b[j], a[i], acc[i][j], 0, 0, 0)
              : __builtin_amdgcn_mfma_f32_16x16x32_bf16(a[i], b[j], acc[i][j], 0, 0, 0);
    }
    __syncthreads();
  }

  if (SWAP) {
    const float scale = (z == 0) ? 0.18033688011112042f : 1.0f;
#pragma unroll
    for (int i = 0; i < 2; i++) {
      const int s = tile_m + wm * 32 + i * 16 + l16;
      const int bb = s >> 11, sl = s & 2047;
#pragma unroll
      for (int j = 0; j < 4; j++) {
        const int nb = tile_n + wn * 64 + j * 16 + quad * 4;
        const float4 b4 = *(const float4*)&bias[nb];
        const int h = nb >> 6, e0 = nb & 63;
        ushort4 o;
        o.x = f2bf((acc[i][j][0] + b4.x) * scale);
        o.y = f2bf((acc[i][j][1] + b4.y) * scale);
        o.z = f2bf((acc[i][j][2] + b4.z) * scale);
        o.w = f2bf((acc[i][j][3] + b4.w) * scale);
        *(ushort4*)&dst[((size_t)(bb * Hn + h) * Sn + sl) * DHn + e0] = o;
      }
    }
  } else {
#pragma unroll
    for (int i = 0; i < 2; i++) {
      const int s0 = tile_m + wm * 32 + i * 16 + quad * 4;
      const int bb = s0 >> 11, sl = s0 & 2047;
#pragma unroll
      for (int j = 0; j < 4; j++) {
        const int n = tile_n + wn * 64 + j * 16 + l16;
        const int h = n >> 6, e = n & 63;
        const float bn = bias[n];
        ushort4 o;
        o.x = f2bf(acc[i][j][0] + bn);
        o.y = f2bf(acc[i][j][1] + bn);
        o.z = f2bf(acc[i][j][2] + bn);
        o.w = f2bf(acc[i][j][3] + bn);
        *(ushort4*)&dst[((size_t)(bb * Hn + h) * DHn + e) * Sn + sl] = o;
      }
    }
  }
}

// ---------------- flash attention: 256 thr / 4 waves, 16 q-rows per wave ----------------
// q-tile 64/block -> grid 2048 blocks (8/CU available). LDS = Ks dbuf 16KB +
// Vs single 9.2KB = 25.6KB -> 6 blocks/CU resident (24 waves/CU vs R0's 16).
// Per-wave live state ~32 VGPR (octx 16 + bq 8 + ap 8) -> no reg pressure.
// V single-buffered: 2 barriers/tile; V global loads for t+1 issued at top of
// tile t (latency hidden under compute), LDS write between the two barriers.
__global__ __launch_bounds__(256) void k_attn(
    const u16* __restrict__ qg, const u16* __restrict__ kg,
    const u16* __restrict__ vg, u16* __restrict__ ctx) {
  const int bh = blockIdx.y;
  const int b = bh >> 4, h = bh & 15;
  const int tid = threadIdx.x;
  const int wave = tid >> 6, lane = tid & 63;
  const int quad = lane >> 4, l16 = lane & 15;
  const int qbase = blockIdx.x * 64 + wave * 16;

  const u16* qp = qg + (size_t)bh * Sn * DHn;
  const u16* kp = kg + (size_t)bh * Sn * DHn;
  const u16* vp = vg + (size_t)bh * DHn * Sn;   // [DH][S]

  __shared__ u16 Ks[2][64 * 64];     // K dbuf, 16 KB, global_load_lds staged
  __shared__ u16 Vs[64 * LDKV];      // V single buffer, 9.2 KB, reg-staged

  const int srow8 = lane >> 3;
  const int gchunk = (lane & 7) ^ srow8;
  const int sw = l16 & 7;

  const int vrow = tid >> 3;         // 0..31
  const int vc = tid & 7;

  // Q fragment: 16 q-rows (l16), dh chunks quad*8 and 32+quad*8
  short8 bq0 = *(const short8*)&qp[(size_t)(qbase + l16) * DHn + quad * 8];
  short8 bq1 = *(const short8*)&qp[(size_t)(qbase + l16) * DHn + 32 + quad * 8];

  f32x4 octx[4];
#pragma unroll
  for (int j = 0; j < 4; j++) octx[j] = (f32x4){0.f, 0.f, 0.f, 0.f};
  float lr = 0.f;

  // prologue: stage K tile 0 (async) + V tile 0 (regs -> LDS)
  {
    const int rbase = wave * 16;
    async16(&kp[(size_t)(rbase + srow8) * DHn + gchunk * 8], &Ks[0][rbase * 64]);
    async16(&kp[(size_t)(rbase + 8 + srow8) * DHn + gchunk * 8], &Ks[0][(rbase + 8) * 64]);
    uint4 v0 = *(const uint4*)&vp[(size_t)vrow * Sn + vc * 8];
    uint4 v1 = *(const uint4*)&vp[(size_t)(32 + vrow) * Sn + vc * 8];
    *(uint4*)&Vs[vrow * LDKV + vc * 8] = v0;
    *(uint4*)&Vs[(32 + vrow) * LDKV + vc * 8] = v1;
  }
  __syncthreads();

  uint4 vv0, vv1;
  for (int kt = 0; kt < Sn / 64; ++kt) {
    const int cur = kt & 1, nxt = cur ^ 1;
    const bool more = (kt + 1 < Sn / 64);
    if (more) {
      const int key1 = (kt + 1) * 64;
      const int rbase = wave * 16;
      async16(&kp[(size_t)(key1 + rbase + srow8) * DHn + gchunk * 8], &Ks[nxt][rbase * 64]);
      async16(&kp[(size_t)(key1 + rbase + 8 + srow8) * DHn + gchunk * 8], &Ks[nxt][(rbase + 8) * 64]);
      vv0 = *(const uint4*)&vp[(size_t)vrow * Sn + key1 + vc * 8];
      vv1 = *(const uint4*)&vp[(size_t)(32 + vrow) * Sn + key1 + vc * 8];
    }

    // QK^T + softmax-numerator for 16 q-rows x 64 keys
    short4v ap[4];
#pragma unroll
    for (int g = 0; g < 4; g++) {
      short8 ka0 = *(const short8*)&Ks[cur][(g * 16 + l16) * 64 + (quad ^ sw) * 8];
      short8 ka1 = *(const short8*)&Ks[cur][(g * 16 + l16) * 64 + ((quad + 4) ^ sw) * 8];
      f32x4 sc = (f32x4){0.f, 0.f, 0.f, 0.f};
      sc = __builtin_amdgcn_mfma_f32_16x16x32_bf16(ka0, bq0, sc, 0, 0, 0);
      sc = __builtin_amdgcn_mfma_f32_16x16x32_bf16(ka1, bq1, sc, 0, 0, 0);
      float p[4];
#pragma unroll
      for (int r = 0; r < 4; r++) p[r] = __builtin_amdgcn_exp2f(sc[r]);
      lr += (p[0] + p[1]) + (p[2] + p[3]);
      ap[g] = __builtin_bit_cast(short4v, (uint2v){pk2(p[0], p[1]), pk2(p[2], p[3])});
    }

    // PV
#pragma unroll
    for (int j = 0; j < 4; j++) {
#pragma unroll
      for (int g = 0; g < 4; g++) {
        short4v vb = *(const short4v*)&Vs[(j * 16 + l16) * LDKV + g * 16 + quad * 4];
        octx[j] = __builtin_amdgcn_mfma_f32_16x16x16bf16_1k(ap[g], vb, octx[j], 0, 0, 0);
      }
    }

    __syncthreads();                  // Vs reads done; Ks[nxt] DMA drained; vv arrived
    if (more) {
      *(uint4*)&Vs[vrow * LDKV + vc * 8] = vv0;
      *(uint4*)&Vs[(32 + vrow) * LDKV + vc * 8] = vv1;
    }
    __syncthreads();                  // Vs[t+1] visible
  }

  // softmax denominator: sum partials across quad groups (keys), broadcast per row
  lr += __shfl_xor(lr, 16, 64);
  lr += __shfl_xor(lr, 32, 64);
  float rl[4];
#pragma unroll
  for (int r = 0; r < 4; r++)
    rl[r] = 1.0f / __shfl(lr, quad * 4 + r, 64);

#pragma unroll
  for (int j = 0; j < 4; j++) {
    const int n = h * DHn + j * 16 + l16;
#pragma unroll
    for (int r = 0; r < 4; r++) {
      const int s = qbase + quad * 4 + r;
      ctx[(size_t)(b * Sn + s) * Dn + n] = f2bf(octx[j][r] * rl[r]);
    }
  }
}

// ---------------- output projection GEMM: 512 thr / 8 waves, swapped epilogue ----------------
__global__ __launch_bounds__(512) void k_gemm_out(
    const u16* __restrict__ A, const u16* __restrict__ WoT,
    const float* __restrict__ bo, float* __restrict__ out) {
  const int tile_m = blockIdx.x * 128;
  const int tile_n = blockIdx.y * 128;
  const int K = Dn;

  __shared__ u16 As[128 * 64];
  __shared__ u16 Bs[128 * 64];

  const int tid = threadIdx.x;
  const int lane = tid & 63;
  const int wave = tid >> 6;
  const int wm = wave & 3, wn = wave >> 2;
  const int quad = lane >> 4, l16 = lane & 15;
  const int srow8 = lane >> 3;
  const int gchunk = (lane & 7) ^ srow8;
  const int sw = l16 & 7;

  f32x4 acc[2][4];
#pragma unroll
  for (int i = 0; i < 2; i++)
#pragma unroll
    for (int j = 0; j < 4; j++) acc[i][j] = (f32x4){0.f, 0.f, 0.f, 0.f};

  for (int k0 = 0; k0 < K; k0 += 64) {
    const int rb = wave * 16;
    async16(&A[(size_t)(tile_m + rb + srow8) * K + k0 + gchunk * 8], &As[rb * 64]);
    async16(&A[(size_t)(tile_m + rb + 8 + srow8) * K + k0 + gchunk * 8], &As[(rb + 8) * 64]);
    async16(&WoT[(size_t)(tile_n + rb + srow8) * K + k0 + gchunk * 8], &Bs[rb * 64]);
    async16(&WoT[(size_t)(tile_n + rb + 8 + srow8) * K + k0 + gchunk * 8], &Bs[(rb + 8) * 64]);
    __syncthreads();
#pragma unroll
    for (int ks = 0; ks < 2; ++ks) {
      short8 a[2], b[4];
#pragma unroll
      for (int i = 0; i < 2; i++)
        a[i] = *(const short8*)&As[(wm * 32 + i * 16 + l16) * 64 + ((ks * 4 + quad) ^ sw) * 8];
#pragma unroll
      for (int j = 0; j < 4; j++)
        b[j] = *(const short8*)&Bs[(wn * 64 + j * 16 + l16) * 64 + ((ks * 4 + quad) ^ sw) * 8];
#pragma unroll
      for (int i = 0; i < 2; i++)
#pragma unroll
        for (int j = 0; j < 4; j++)
          acc[i][j] = __builtin_amdgcn_mfma_f32_16x16x32_bf16(b[j], a[i], acc[i][j], 0, 0, 0);
    }
    __syncthreads();
  }

#pragma unroll
  for (int i = 0; i < 2; i++) {
    const int s = tile_m + wm * 32 + i * 16 + l16;
#pragma unroll
    for (int j = 0; j < 4; j++) {
      const int nb = tile_n + wn * 64 + j * 16 + quad * 4;
      const float4 b4 = *(const float4*)&bo[nb];
      float4 o;
      o.x = acc[i][j][0] + b4.x;
      o.y = acc[i][j][1] + b4.y;
      o.z = acc[i][j][2] + b4.z;
      o.w = acc[i][j][3] + b4.w;
      *(float4*)&out[(size_t)s * Dn + nb] = o;
    }
  }
}

extern "C" void kernel_launch(void* const* d_in, const int* in_sizes, int n_in,
                              void* d_out, int out_size, void* d_ws, size_t ws_size,
                              hipStream_t stream) {
  const float* x  = (const float*)d_in[0];
  const float* Wq = (const float*)d_in[1];
  const float* bq = (const float*)d_in[2];
  const float* Wk = (const float*)d_in[3];
  const float* bk = (const float*)d_in[4];
  const float* Wv = (const float*)d_in[5];
  const float* bv = (const float*)d_in[6];
  const float* Wo = (const float*)d_in[7];
  const float* bo = (const float*)d_in[8];
  float* out = (float*)d_out;

  // workspace carve-up (ctx aliases xb: xb dead after k_gemm_qkv) — ~75.5 MB
  char* ws = (char*)d_ws;
  u16* xb  = (u16*)ws;  ws += (size_t)Mn * Dn * 2;
  u16* WqT = (u16*)ws;  ws += (size_t)Dn * Dn * 2;
  u16* WkT = (u16*)ws;  ws += (size_t)Dn * Dn * 2;
  u16* WvT = (u16*)ws;  ws += (size_t)Dn * Dn * 2;
  u16* WoT = (u16*)ws;  ws += (size_t)Dn * Dn * 2;
  u16* qb  = (u16*)ws;  ws += (size_t)Mn * Dn * 2;
  u16* kb  = (u16*)ws;  ws += (size_t)Mn * Dn * 2;
  u16* vtb = (u16*)ws;  ws += (size_t)Mn * Dn * 2;
  u16* ctx = xb;        // alias

  k_convert_x<<<(Mn * Dn / 4) / 256, 256, 0, stream>>>((const float4*)x, (ushort4*)xb, Mn * Dn / 4);
  k_convert_w<<<1024, 256, 0, stream>>>(Wq, Wk, Wv, Wo, WqT, WkT, WvT, WoT);

  dim3 g1(Mn / 128, Dn / 128, 2);
  k_gemm_qkv<1><<<g1, 512, 0, stream>>>(xb, WqT, WkT, bq, bk, qb, kb);
  dim3 g1v(Mn / 128, Dn / 128, 1);
  k_gemm_qkv<0><<<g1v, 512, 0, stream>>>(xb, WvT, nullptr, bv, nullptr, vtb, nullptr);

  dim3 g2(Sn / 64, Bn * Hn);
  k_attn<<<g2, 256, 0, stream>>>(qb, kb, vtb, ctx);

  dim3 g3(Mn / 128, Dn / 128);
  k_gemm_out<<<g3, 512, 0, stream>>>(ctx, WoT, bo, out);
}

// Round 3
// 307.258 us; speedup vs baseline: 2.7377x; 1.0045x over previous
//
#include <hip/hip_runtime.h>

// MHA: B=4 S=2048 D=1024 H=16 DH=64. Full bf16-MFMA pipeline (fp32 accum).

#define Bn  4
#define Sn  2048
#define Dn  1024
#define Hn  16
#define DHn 64
#define Mn  (Bn*Sn)          // 8192 rows
#define LDKV 72              // attn V LDS row stride (ushorts)

typedef unsigned short u16;
typedef __attribute__((ext_vector_type(8))) short short8;   // 8 x bf16 (4 VGPRs)
typedef __attribute__((ext_vector_type(4))) short short4v;  // 4 x bf16 (2 VGPRs)
typedef __attribute__((ext_vector_type(4))) float f32x4;    // MFMA C/D frag
typedef __attribute__((ext_vector_type(2))) unsigned int uint2v;

__device__ __forceinline__ u16 f2bf(float f) {
  unsigned u = __float_as_uint(f);
  return (u16)((u + 0x7FFFu + ((u >> 16) & 1u)) >> 16);   // RNE
}

// async 16B/lane global->LDS DMA; lds dest = wave-uniform base + lane*16
__device__ __forceinline__ void async16(const void* g, void* l) {
  __builtin_amdgcn_global_load_lds(
      (const __attribute__((address_space(1))) void*)g,
      (__attribute__((address_space(3))) void*)l, 16, 0, 0);
}

// pack 2 fp32 -> 2 bf16 (truncation) in one v_perm_b32
__device__ __forceinline__ unsigned pk2(float a, float b) {
  return __builtin_amdgcn_perm(__float_as_uint(b), __float_as_uint(a), 0x07060302u);
}

// ---------------- convert: x (f32) -> xb (bf16) ----------------
__global__ __launch_bounds__(256) void k_convert_x(
    const float4* __restrict__ x, ushort4* __restrict__ xb, int n4) {
  int i = blockIdx.x * 256 + threadIdx.x;
  if (i < n4) {
    float4 f = x[i];
    ushort4 o;
    o.x = f2bf(f.x); o.y = f2bf(f.y); o.z = f2bf(f.z); o.w = f2bf(f.w);
    xb[i] = o;
  }
}

// ---- convert+transpose weights to [N][K] bf16 via LDS 64x64 tiles ----
__global__ __launch_bounds__(256) void k_convert_w(
    const float* __restrict__ Wq, const float* __restrict__ Wk,
    const float* __restrict__ Wv, const float* __restrict__ Wo,
    u16* __restrict__ WqT, u16* __restrict__ WkT,
    u16* __restrict__ WvT, u16* __restrict__ WoT) {
  __shared__ float t[64][65];
  const int bid = blockIdx.x;          // 0..1023
  const int wsel = bid >> 8;           // 0..3
  const int idx = bid & 255;
  const int tid = threadIdx.x;
  const int c = tid & 63;
  const int r4 = tid >> 6;             // 0..3

  if (wsel < 3) {
    const float* W = (wsel == 0) ? Wq : (wsel == 1) ? Wk : Wv;
    u16* T = (wsel == 0) ? WqT : (wsel == 1) ? WkT : WvT;
    const int h = idx >> 4;
    const int d0 = (idx & 15) * 64;
    const float* src = W + (size_t)h * (Dn * DHn) + (size_t)d0 * DHn;
#pragma unroll
    for (int r = 0; r < 16; r++) {
      int row = r * 4 + r4;
      t[row][c] = src[row * DHn + c];
    }
    __syncthreads();
    u16* dst = T + (size_t)(h * 64) * Dn + d0;
#pragma unroll
    for (int r = 0; r < 16; r++) {
      int erow = r * 4 + r4;
      dst[(size_t)erow * Dn + c] = f2bf(t[c][erow]);
    }
  } else {
    const int n0 = (idx >> 4) * 64;
    const int d0 = (idx & 15) * 64;
#pragma unroll
    for (int r = 0; r < 16; r++) {
      int row = r * 4 + r4;
      t[row][c] = Wo[(size_t)(d0 + row) * Dn + n0 + c];
    }
    __syncthreads();
#pragma unroll
    for (int r = 0; r < 16; r++) {
      int nrow = r * 4 + r4;
      WoT[(size_t)(n0 + nrow) * Dn + d0 + c] = f2bf(t[c][nrow]);
    }
  }
}

// ---------------- QKV projection GEMM: 512 thr / 8 waves, 128x128 tile ----------------
template<int SWAP>
__global__ __launch_bounds__(512) void k_gemm_qkv(
    const u16* __restrict__ A, const u16* __restrict__ B0T,
    const u16* __restrict__ B1T, const float* __restrict__ bias0,
    const float* __restrict__ bias1, u16* __restrict__ out0,
    u16* __restrict__ out1) {
  const int z = blockIdx.z;
  const u16* BT = z ? B1T : B0T;
  const float* bias = z ? bias1 : bias0;
  u16* dst = z ? out1 : out0;
  const int tile_m = blockIdx.x * 128;
  const int tile_n = blockIdx.y * 128;
  const int K = Dn;

  __shared__ u16 As[128 * 64];
  __shared__ u16 Bs[128 * 64];

  const int tid = threadIdx.x;
  const int lane = tid & 63;
  const int wave = tid >> 6;                    // 0..7
  const int wm = wave & 3, wn = wave >> 2;
  const int quad = lane >> 4, l16 = lane & 15;
  const int srow8 = lane >> 3;
  const int gchunk = (lane & 7) ^ srow8;
  const int sw = l16 & 7;

  f32x4 acc[2][4];
#pragma unroll
  for (int i = 0; i < 2; i++)
#pragma unroll
    for (int j = 0; j < 4; j++) acc[i][j] = (f32x4){0.f, 0.f, 0.f, 0.f};

  for (int k0 = 0; k0 < K; k0 += 64) {
    const int rb = wave * 16;
    async16(&A[(size_t)(tile_m + rb + srow8) * K + k0 + gchunk * 8], &As[rb * 64]);
    async16(&A[(size_t)(tile_m + rb + 8 + srow8) * K + k0 + gchunk * 8], &As[(rb + 8) * 64]);
    async16(&BT[(size_t)(tile_n + rb + srow8) * K + k0 + gchunk * 8], &Bs[rb * 64]);
    async16(&BT[(size_t)(tile_n + rb + 8 + srow8) * K + k0 + gchunk * 8], &Bs[(rb + 8) * 64]);
    __syncthreads();
#pragma unroll
    for (int ks = 0; ks < 2; ++ks) {
      short8 a[2], b[4];
#pragma unroll
      for (int i = 0; i < 2; i++)
        a[i] = *(const short8*)&As[(wm * 32 + i * 16 + l16) * 64 + ((ks * 4 + quad) ^ sw) * 8];
#pragma unroll
      for (int j = 0; j < 4; j++)
        b[j] = *(const short8*)&Bs[(wn * 64 + j * 16 + l16) * 64 + ((ks * 4 + quad) ^ sw) * 8];
#pragma unroll
      for (int i = 0; i < 2; i++)
#pragma unroll
        for (int j = 0; j < 4; j++)
          acc[i][j] = SWAP
              ? __builtin_amdgcn_mfma_f32_16x16x32_bf16(b[j], a[i], acc[i][j], 0, 0, 0)
              : __builtin_amdgcn_mfma_f32_16x16x32_bf16(a[i], b[j], acc[i][j], 0, 0, 0);
    }
    __syncthreads();
  }

  if (SWAP) {
    const float scale = (z == 0) ? 0.18033688011112042f : 1.0f;
#pragma unroll
    for (int i = 0; i < 2; i++) {
      const int s = tile_m + wm * 32 + i * 16 + l16;
      const int bb = s >> 11, sl = s & 2047;
#pragma unroll
      for (int j = 0; j < 4; j++) {
        const int nb = tile_n + wn * 64 + j * 16 + quad * 4;
        const float4 b4 = *(const float4*)&bias[nb];
        const int h = nb >> 6, e0 = nb & 63;
        ushort4 o;
        o.x = f2bf((acc[i][j][0] + b4.x) * scale);
        o.y = f2bf((acc[i][j][1] + b4.y) * scale);
        o.z = f2bf((acc[i][j][2] + b4.z) * scale);
        o.w = f2bf((acc[i][j][3] + b4.w) * scale);
        *(ushort4*)&dst[((size_t)(bb * Hn + h) * Sn + sl) * DHn + e0] = o;
      }
    }
  } else {
#pragma unroll
    for (int i = 0; i < 2; i++) {
      const int s0 = tile_m + wm * 32 + i * 16 + quad * 4;
      const int bb = s0 >> 11, sl = s0 & 2047;
#pragma unroll
      for (int j = 0; j < 4; j++) {
        const int n = tile_n + wn * 64 + j * 16 + l16;
        const int h = n >> 6, e = n & 63;
        const float bn = bias[n];
        ushort4 o;
        o.x = f2bf(acc[i][j][0] + bn);
        o.y = f2bf(acc[i][j][1] + bn);
        o.z = f2bf(acc[i][j][2] + bn);
        o.w = f2bf(acc[i][j][3] + bn);
        *(ushort4*)&dst[((size_t)(bb * Hn + h) * DHn + e) * Sn + sl] = o;
      }
    }
  }
}

// ---------------- flash attention: 256 thr / 4 waves, KEY-SPLIT ----------------
// Wave (qw, kh): 32 q-rows (qw in 0..1) x 32 keys (kh in 0..1) of each 64-key
// tile. Per-wave ratios (LDS reads : MFMA : exp2) identical to the 107us R0
// kernel; total LDS traffic / MFMA / exp2 unchanged. q-tile 64 -> 2048 blocks.
// LDS = Ks dbuf 16KB + Vs single 9.2KB = 25.6KB -> 6 blocks/CU = 24 waves/CU
// (R0: 16). 2-way partial merge (octx via Ks reuse, lr via Vs) at the end.
__global__ __launch_bounds__(256) void k_attn(
    const u16* __restrict__ qg, const u16* __restrict__ kg,
    const u16* __restrict__ vg, u16* __restrict__ ctx) {
  const int bh = blockIdx.y;
  const int b = bh >> 4, h = bh & 15;
  const int tid = threadIdx.x;
  const int wave = tid >> 6, lane = tid & 63;
  const int quad = lane >> 4, l16 = lane & 15;
  const int kh = wave >> 1;                 // key half: 0 => keys 0-31, 1 => 32-63
  const int qw = wave & 1;                  // q sub-tile
  const int qbase = blockIdx.x * 64 + qw * 32;

  const u16* qp = qg + (size_t)bh * Sn * DHn;
  const u16* kp = kg + (size_t)bh * Sn * DHn;
  const u16* vp = vg + (size_t)bh * DHn * Sn;   // [DH][S]

  __shared__ u16 Ks[2][64 * 64];     // K dbuf, 16 KB, global_load_lds staged
  __shared__ u16 Vs[64 * LDKV];      // V single buffer, 9.2 KB, reg-staged

  const int srow8 = lane >> 3;
  const int gchunk = (lane & 7) ^ srow8;
  const int sw = l16 & 7;

  const int vrow = tid >> 3;         // 0..31
  const int vc = tid & 7;

  // Q fragments: 2 groups of 16 q-rows
  short8 bq[2][2];
#pragma unroll
  for (int g2 = 0; g2 < 2; g2++) {
    bq[g2][0] = *(const short8*)&qp[(size_t)(qbase + g2 * 16 + l16) * DHn + quad * 8];
    bq[g2][1] = *(const short8*)&qp[(size_t)(qbase + g2 * 16 + l16) * DHn + 32 + quad * 8];
  }

  f32x4 octx[2][4];
#pragma unroll
  for (int g2 = 0; g2 < 2; g2++)
#pragma unroll
    for (int j = 0; j < 4; j++) octx[g2][j] = (f32x4){0.f, 0.f, 0.f, 0.f};
  float lr[2] = {0.f, 0.f};

  // prologue: stage K tile 0 (async, 16 rows/wave) + V tile 0 (regs -> LDS)
  {
    const int rbase = wave * 16;
    async16(&kp[(size_t)(rbase + srow8) * DHn + gchunk * 8], &Ks[0][rbase * 64]);
    async16(&kp[(size_t)(rbase + 8 + srow8) * DHn + gchunk * 8], &Ks[0][(rbase + 8) * 64]);
    uint4 v0 = *(const uint4*)&vp[(size_t)vrow * Sn + vc * 8];
    uint4 v1 = *(const uint4*)&vp[(size_t)(32 + vrow) * Sn + vc * 8];
    *(uint4*)&Vs[vrow * LDKV + vc * 8] = v0;
    *(uint4*)&Vs[(32 + vrow) * LDKV + vc * 8] = v1;
  }
  __syncthreads();

  uint4 vv0, vv1;
  for (int kt = 0; kt < Sn / 64; ++kt) {
    const int cur = kt & 1, nxt = cur ^ 1;
    const bool more = (kt + 1 < Sn / 64);
    if (more) {
      const int key1 = (kt + 1) * 64;
      const int rbase = wave * 16;
      async16(&kp[(size_t)(key1 + rbase + srow8) * DHn + gchunk * 8], &Ks[nxt][rbase * 64]);
      async16(&kp[(size_t)(key1 + rbase + 8 + srow8) * DHn + gchunk * 8], &Ks[nxt][(rbase + 8) * 64]);
      vv0 = *(const uint4*)&vp[(size_t)vrow * Sn + key1 + vc * 8];
      vv1 = *(const uint4*)&vp[(size_t)(32 + vrow) * Sn + key1 + vc * 8];
    }

    // QK^T + softmax numerator: 32 q-rows x 32 keys (this wave's half)
    short4v ap[2][2];
#pragma unroll
    for (int g = 0; g < 2; g++) {
      const int krow = kh * 32 + g * 16 + l16;
      short8 ka0 = *(const short8*)&Ks[cur][krow * 64 + (quad ^ sw) * 8];
      short8 ka1 = *(const short8*)&Ks[cur][krow * 64 + ((quad + 4) ^ sw) * 8];
#pragma unroll
      for (int g2 = 0; g2 < 2; g2++) {
        f32x4 sc = (f32x4){0.f, 0.f, 0.f, 0.f};
        sc = __builtin_amdgcn_mfma_f32_16x16x32_bf16(ka0, bq[g2][0], sc, 0, 0, 0);
        sc = __builtin_amdgcn_mfma_f32_16x16x32_bf16(ka1, bq[g2][1], sc, 0, 0, 0);
        float p[4];
#pragma unroll
        for (int r = 0; r < 4; r++) p[r] = __builtin_amdgcn_exp2f(sc[r]);
        lr[g2] += (p[0] + p[1]) + (p[2] + p[3]);
        ap[g2][g] = __builtin_bit_cast(short4v, (uint2v){pk2(p[0], p[1]), pk2(p[2], p[3])});
      }
    }

    // PV over this wave's 32 keys
#pragma unroll
    for (int j = 0; j < 4; j++) {
#pragma unroll
      for (int g = 0; g < 2; g++) {
        short4v vb = *(const short4v*)&Vs[(j * 16 + l16) * LDKV + kh * 32 + g * 16 + quad * 4];
        octx[0][j] = __builtin_amdgcn_mfma_f32_16x16x16bf16_1k(ap[0][g], vb, octx[0][j], 0, 0, 0);
        octx[1][j] = __builtin_amdgcn_mfma_f32_16x16x16bf16_1k(ap[1][g], vb, octx[1][j], 0, 0, 0);
      }
    }

    __syncthreads();                  // Vs reads done; Ks[nxt] DMA drained; vv arrived
    if (more) {
      *(uint4*)&Vs[vrow * LDKV + vc * 8] = vv0;
      *(uint4*)&Vs[(32 + vrow) * LDKV + vc * 8] = vv1;
    }
    __syncthreads();                  // Vs[t+1] visible
  }

  // ---- merge key-half partials (kh=1 -> kh=0) via LDS (Ks reuse, 16 KB) ----
  float* mbuf = (float*)&Ks[0][0];          // 2qw x 2g2 x 4j x 64lane x f32x4 = 16 KB
  float* lrbuf = (float*)&Vs[0];            // 4 x 64 floats = 1 KB
  if (kh == 1) {
#pragma unroll
    for (int g2 = 0; g2 < 2; g2++) {
#pragma unroll
      for (int j = 0; j < 4; j++)
        *(f32x4*)&mbuf[(((qw * 2 + g2) * 4 + j) * 64 + lane) * 4] = octx[g2][j];
      lrbuf[(qw * 2 + g2) * 64 + lane] = lr[g2];
    }
  }
  __syncthreads();
  if (kh == 1) return;

#pragma unroll
  for (int g2 = 0; g2 < 2; g2++) {
#pragma unroll
    for (int j = 0; j < 4; j++) {
      f32x4 o = *(const f32x4*)&mbuf[(((qw * 2 + g2) * 4 + j) * 64 + lane) * 4];
      octx[g2][j][0] += o[0]; octx[g2][j][1] += o[1];
      octx[g2][j][2] += o[2]; octx[g2][j][3] += o[3];
    }
    lr[g2] += lrbuf[(qw * 2 + g2) * 64 + lane];
  }

  // softmax denominator: sum across quad groups (keys), broadcast per row
#pragma unroll
  for (int g2 = 0; g2 < 2; g2++) {
    lr[g2] += __shfl_xor(lr[g2], 16, 64);
    lr[g2] += __shfl_xor(lr[g2], 32, 64);
  }
  float rl[2][4];
#pragma unroll
  for (int g2 = 0; g2 < 2; g2++)
#pragma unroll
    for (int r = 0; r < 4; r++)
      rl[g2][r] = 1.0f / __shfl(lr[g2], quad * 4 + r, 64);

#pragma unroll
  for (int g2 = 0; g2 < 2; g2++)
#pragma unroll
    for (int j = 0; j < 4; j++) {
      const int n = h * DHn + j * 16 + l16;
#pragma unroll
      for (int r = 0; r < 4; r++) {
        const int s = qbase + g2 * 16 + quad * 4 + r;
        ctx[(size_t)(b * Sn + s) * Dn + n] = f2bf(octx[g2][j][r] * rl[g2][r]);
      }
    }
}

// ---------------- output projection GEMM: 512 thr / 8 waves, swapped epilogue ----------------
__global__ __launch_bounds__(512) void k_gemm_out(
    const u16* __restrict__ A, const u16* __restrict__ WoT,
    const float* __restrict__ bo, float* __restrict__ out) {
  const int tile_m = blockIdx.x * 128;
  const int tile_n = blockIdx.y * 128;
  const int K = Dn;

  __shared__ u16 As[128 * 64];
  __shared__ u16 Bs[128 * 64];

  const int tid = threadIdx.x;
  const int lane = tid & 63;
  const int wave = tid >> 6;
  const int wm = wave & 3, wn = wave >> 2;
  const int quad = lane >> 4, l16 = lane & 15;
  const int srow8 = lane >> 3;
  const int gchunk = (lane & 7) ^ srow8;
  const int sw = l16 & 7;

  f32x4 acc[2][4];
#pragma unroll
  for (int i = 0; i < 2; i++)
#pragma unroll
    for (int j = 0; j < 4; j++) acc[i][j] = (f32x4){0.f, 0.f, 0.f, 0.f};

  for (int k0 = 0; k0 < K; k0 += 64) {
    const int rb = wave * 16;
    async16(&A[(size_t)(tile_m + rb + srow8) * K + k0 + gchunk * 8], &As[rb * 64]);
    async16(&A[(size_t)(tile_m + rb + 8 + srow8) * K + k0 + gchunk * 8], &As[(rb + 8) * 64]);
    async16(&WoT[(size_t)(tile_n + rb + srow8) * K + k0 + gchunk * 8], &Bs[rb * 64]);
    async16(&WoT[(size_t)(tile_n + rb + 8 + srow8) * K + k0 + gchunk * 8], &Bs[(rb + 8) * 64]);
    __syncthreads();
#pragma unroll
    for (int ks = 0; ks < 2; ++ks) {
      short8 a[2], b[4];
#pragma unroll
      for (int i = 0; i < 2; i++)
        a[i] = *(const short8*)&As[(wm * 32 + i * 16 + l16) * 64 + ((ks * 4 + quad) ^ sw) * 8];
#pragma unroll
      for (int j = 0; j < 4; j++)
        b[j] = *(const short8*)&Bs[(wn * 64 + j * 16 + l16) * 64 + ((ks * 4 + quad) ^ sw) * 8];
#pragma unroll
      for (int i = 0; i < 2; i++)
#pragma unroll
        for (int j = 0; j < 4; j++)
          acc[i][j] = __builtin_amdgcn_mfma_f32_16x16x32_bf16(b[j], a[i], acc[i][j], 0, 0, 0);
    }
    __syncthreads();
  }

#pragma unroll
  for (int i = 0; i < 2; i++) {
    const int s = tile_m + wm * 32 + i * 16 + l16;
#pragma unroll
    for (int j = 0; j < 4; j++) {
      const int nb = tile_n + wn * 64 + j * 16 + quad * 4;
      const float4 b4 = *(const float4*)&bo[nb];
      float4 o;
      o.x = acc[i][j][0] + b4.x;
      o.y = acc[i][j][1] + b4.y;
      o.z = acc[i][j][2] + b4.z;
      o.w = acc[i][j][3] + b4.w;
      *(float4*)&out[(size_t)s * Dn + nb] = o;
    }
  }
}

extern "C" void kernel_launch(void* const* d_in, const int* in_sizes, int n_in,
                              void* d_out, int out_size, void* d_ws, size_t ws_size,
                              hipStream_t stream) {
  const float* x  = (const float*)d_in[0];
  const float* Wq = (const float*)d_in[1];
  const float* bq = (const float*)d_in[2];
  const float* Wk = (const float*)d_in[3];
  const float* bk = (const float*)d_in[4];
  const float* Wv = (const float*)d_in[5];
  const float* bv = (const float*)d_in[6];
  const float* Wo = (const float*)d_in[7];
  const float* bo = (const float*)d_in[8];
  float* out = (float*)d_out;

  // workspace carve-up (ctx aliases xb: xb dead after k_gemm_qkv) — ~75.5 MB
  char* ws = (char*)d_ws;
  u16* xb  = (u16*)ws;  ws += (size_t)Mn * Dn * 2;
  u16* WqT = (u16*)ws;  ws += (size_t)Dn * Dn * 2;
  u16* WkT = (u16*)ws;  ws += (size_t)Dn * Dn * 2;
  u16* WvT = (u16*)ws;  ws += (size_t)Dn * Dn * 2;
  u16* WoT = (u16*)ws;  ws += (size_t)Dn * Dn * 2;
  u16* qb  = (u16*)ws;  ws += (size_t)Mn * Dn * 2;
  u16* kb  = (u16*)ws;  ws += (size_t)Mn * Dn * 2;
  u16* vtb = (u16*)ws;  ws += (size_t)Mn * Dn * 2;
  u16* ctx = xb;        // alias

  k_convert_x<<<(Mn * Dn / 4) / 256, 256, 0, stream>>>((const float4*)x, (ushort4*)xb, Mn * Dn / 4);
  k_convert_w<<<1024, 256, 0, stream>>>(Wq, Wk, Wv, Wo, WqT, WkT, WvT, WoT);

  dim3 g1(Mn / 128, Dn / 128, 2);
  k_gemm_qkv<1><<<g1, 512, 0, stream>>>(xb, WqT, WkT, bq, bk, qb, kb);
  dim3 g1v(Mn / 128, Dn / 128, 1);
  k_gemm_qkv<0><<<g1v, 512, 0, stream>>>(xb, WvT, nullptr, bv, nullptr, vtb, nullptr);

  dim3 g2(Sn / 64, Bn * Hn);
  k_attn<<<g2, 256, 0, stream>>>(qb, kb, vtb, ctx);

  dim3 g3(Mn / 128, Dn / 128);
  k_gemm_out<<<g3, 512, 0, stream>>>(ctx, WoT, bo, out);
}

// Round 4
// 304.836 us; speedup vs baseline: 2.7595x; 1.0079x over previous
//
#include <hip/hip_runtime.h>

// MHA: B=4 S=2048 D=1024 H=16 DH=64. Full bf16-MFMA pipeline (fp32 accum).

#define Bn  4
#define Sn  2048
#define Dn  1024
#define Hn  16
#define DHn 64
#define Mn  (Bn*Sn)          // 8192 rows

typedef unsigned short u16;
typedef __attribute__((ext_vector_type(8))) short short8;   // 8 x bf16 (4 VGPRs)
typedef __attribute__((ext_vector_type(4))) short short4v;  // 4 x bf16 (2 VGPRs)
typedef __attribute__((ext_vector_type(4))) float f32x4;    // MFMA C/D frag
typedef __attribute__((ext_vector_type(2))) unsigned int uint2v;

__device__ __forceinline__ u16 f2bf(float f) {
  unsigned u = __float_as_uint(f);
  return (u16)((u + 0x7FFFu + ((u >> 16) & 1u)) >> 16);   // RNE
}

// async 16B/lane global->LDS DMA; lds dest = wave-uniform base + lane*16
__device__ __forceinline__ void async16(const void* g, void* l) {
  __builtin_amdgcn_global_load_lds(
      (const __attribute__((address_space(1))) void*)g,
      (__attribute__((address_space(3))) void*)l, 16, 0, 0);
}

// pack 2 fp32 -> 2 bf16 (truncation) in one v_perm_b32
__device__ __forceinline__ unsigned pk2(float a, float b) {
  return __builtin_amdgcn_perm(__float_as_uint(b), __float_as_uint(a), 0x07060302u);
}

// ---------------- convert: x (f32) -> xb (bf16) ----------------
__global__ __launch_bounds__(256) void k_convert_x(
    const float4* __restrict__ x, ushort4* __restrict__ xb, int n4) {
  int i = blockIdx.x * 256 + threadIdx.x;
  if (i < n4) {
    float4 f = x[i];
    ushort4 o;
    o.x = f2bf(f.x); o.y = f2bf(f.y); o.z = f2bf(f.z); o.w = f2bf(f.w);
    xb[i] = o;
  }
}

// ---- convert+transpose weights to [N][K] bf16 via LDS 64x64 tiles ----
__global__ __launch_bounds__(256) void k_convert_w(
    const float* __restrict__ Wq, const float* __restrict__ Wk,
    const float* __restrict__ Wv, const float* __restrict__ Wo,
    u16* __restrict__ WqT, u16* __restrict__ WkT,
    u16* __restrict__ WvT, u16* __restrict__ WoT) {
  __shared__ float t[64][65];
  const int bid = blockIdx.x;          // 0..1023
  const int wsel = bid >> 8;           // 0..3
  const int idx = bid & 255;
  const int tid = threadIdx.x;
  const int c = tid & 63;
  const int r4 = tid >> 6;             // 0..3

  if (wsel < 3) {
    const float* W = (wsel == 0) ? Wq : (wsel == 1) ? Wk : Wv;
    u16* T = (wsel == 0) ? WqT : (wsel == 1) ? WkT : WvT;
    const int h = idx >> 4;
    const int d0 = (idx & 15) * 64;
    const float* src = W + (size_t)h * (Dn * DHn) + (size_t)d0 * DHn;
#pragma unroll
    for (int r = 0; r < 16; r++) {
      int row = r * 4 + r4;
      t[row][c] = src[row * DHn + c];
    }
    __syncthreads();
    u16* dst = T + (size_t)(h * 64) * Dn + d0;
#pragma unroll
    for (int r = 0; r < 16; r++) {
      int erow = r * 4 + r4;
      dst[(size_t)erow * Dn + c] = f2bf(t[c][erow]);
    }
  } else {
    const int n0 = (idx >> 4) * 64;
    const int d0 = (idx & 15) * 64;
#pragma unroll
    for (int r = 0; r < 16; r++) {
      int row = r * 4 + r4;
      t[row][c] = Wo[(size_t)(d0 + row) * Dn + n0 + c];
    }
    __syncthreads();
#pragma unroll
    for (int r = 0; r < 16; r++) {
      int nrow = r * 4 + r4;
      WoT[(size_t)(n0 + nrow) * Dn + d0 + c] = f2bf(t[c][nrow]);
    }
  }
}

// ---------------- QKV projection GEMM: 512 thr / 8 waves, 128x128 tile ----------------
// Single dispatch, z = 0(q) / 1(k) / 2(v). All use swapped MFMA (D^T: lane
// holds 4 contiguous n). q,k epilogue: ushort4 to [B,H,S,DH]; v epilogue:
// 4 scalar stores to [B,H,DH,S] (transposed layout for attention's V).
__global__ __launch_bounds__(512) void k_gemm_qkv(
    const u16* __restrict__ A, const u16* __restrict__ WqT,
    const u16* __restrict__ WkT, const u16* __restrict__ WvT,
    const float* __restrict__ bqv, const float* __restrict__ bkv,
    const float* __restrict__ bvv, u16* __restrict__ qb,
    u16* __restrict__ kb, u16* __restrict__ vtb) {
  const int z = blockIdx.z;
  const u16* BT = (z == 0) ? WqT : (z == 1) ? WkT : WvT;
  const float* bias = (z == 0) ? bqv : (z == 1) ? bkv : bvv;
  const int tile_m = blockIdx.x * 128;
  const int tile_n = blockIdx.y * 128;
  const int K = Dn;

  __shared__ u16 As[128 * 64];
  __shared__ u16 Bs[128 * 64];

  const int tid = threadIdx.x;
  const int lane = tid & 63;
  const int wave = tid >> 6;                    // 0..7
  const int wm = wave & 3, wn = wave >> 2;
  const int quad = lane >> 4, l16 = lane & 15;
  const int srow8 = lane >> 3;
  const int gchunk = (lane & 7) ^ srow8;
  const int sw = l16 & 7;

  f32x4 acc[2][4];
#pragma unroll
  for (int i = 0; i < 2; i++)
#pragma unroll
    for (int j = 0; j < 4; j++) acc[i][j] = (f32x4){0.f, 0.f, 0.f, 0.f};

  for (int k0 = 0; k0 < K; k0 += 64) {
    const int rb = wave * 16;
    async16(&A[(size_t)(tile_m + rb + srow8) * K + k0 + gchunk * 8], &As[rb * 64]);
    async16(&A[(size_t)(tile_m + rb + 8 + srow8) * K + k0 + gchunk * 8], &As[(rb + 8) * 64]);
    async16(&BT[(size_t)(tile_n + rb + srow8) * K + k0 + gchunk * 8], &Bs[rb * 64]);
    async16(&BT[(size_t)(tile_n + rb + 8 + srow8) * K + k0 + gchunk * 8], &Bs[(rb + 8) * 64]);
    __syncthreads();
#pragma unroll
    for (int ks = 0; ks < 2; ++ks) {
      short8 a[2], b[4];
#pragma unroll
      for (int i = 0; i < 2; i++)
        a[i] = *(const short8*)&As[(wm * 32 + i * 16 + l16) * 64 + ((ks * 4 + quad) ^ sw) * 8];
#pragma unroll
      for (int j = 0; j < 4; j++)
        b[j] = *(const short8*)&Bs[(wn * 64 + j * 16 + l16) * 64 + ((ks * 4 + quad) ^ sw) * 8];
#pragma unroll
      for (int i = 0; i < 2; i++)
#pragma unroll
        for (int j = 0; j < 4; j++)
          acc[i][j] = __builtin_amdgcn_mfma_f32_16x16x32_bf16(b[j], a[i], acc[i][j], 0, 0, 0);
    }
    __syncthreads();
  }

  const float scale = (z == 0) ? 0.18033688011112042f : 1.0f;
  if (z < 2) {
    u16* dst = z ? kb : qb;
#pragma unroll
    for (int i = 0; i < 2; i++) {
      const int s = tile_m + wm * 32 + i * 16 + l16;
      const int bb = s >> 11, sl = s & 2047;
#pragma unroll
      for (int j = 0; j < 4; j++) {
        const int nb = tile_n + wn * 64 + j * 16 + quad * 4;
        const float4 b4 = *(const float4*)&bias[nb];
        const int h = nb >> 6, e0 = nb & 63;
        ushort4 o;
        o.x = f2bf((acc[i][j][0] + b4.x) * scale);
        o.y = f2bf((acc[i][j][1] + b4.y) * scale);
        o.z = f2bf((acc[i][j][2] + b4.z) * scale);
        o.w = f2bf((acc[i][j][3] + b4.w) * scale);
        *(ushort4*)&dst[((size_t)(bb * Hn + h) * Sn + sl) * DHn + e0] = o;
      }
    }
  } else {
#pragma unroll
    for (int i = 0; i < 2; i++) {
      const int s = tile_m + wm * 32 + i * 16 + l16;
      const int bb = s >> 11, sl = s & 2047;
#pragma unroll
      for (int j = 0; j < 4; j++) {
        const int nb = tile_n + wn * 64 + j * 16 + quad * 4;
        const float4 b4 = *(const float4*)&bias[nb];
        const int h = nb >> 6, e0 = nb & 63;
        u16* vd = &vtb[((size_t)(bb * Hn + h) * DHn + e0) * Sn + sl];
        vd[0]            = f2bf(acc[i][j][0] + b4.x);
        vd[(size_t)Sn]   = f2bf(acc[i][j][1] + b4.y);
        vd[(size_t)2*Sn] = f2bf(acc[i][j][2] + b4.z);
        vd[(size_t)3*Sn] = f2bf(acc[i][j][3] + b4.w);
      }
    }
  }
}

// ---------------- flash attention: 256 thr / 4 waves, R0 structure ----------------
// 4 waves x 32 q-rows, full 64 keys/tile (the 107.5us ratios). Changes vs R0:
//  - V staged via global_load_lds dbuf (pre-swizzled source, XOR read) —
//    removes per-tile vv global loads + 2 ds_write_b128 + addressing.
//  - lr accumulated via MFMA with ones-B (octl) — removes 24 VALU adds/tile
//    and the whole epilogue shuffle broadcast.
//  - XCD swizzle: 16 q-blocks of one (b,h) share an XCD L2 (8 bh-streams x
//    512KB = 4MB per XCD).
//  - setprio(1) around the PV MFMA cluster.
__global__ __launch_bounds__(256) void k_attn(
    const u16* __restrict__ qg, const u16* __restrict__ kg,
    const u16* __restrict__ vg, u16* __restrict__ ctx) {
  const int p = blockIdx.x;                         // 0..1023
  const int logical = (p & 7) * 128 + (p >> 3);     // same-bh blocks -> same XCD
  const int bh = logical >> 4;
  const int b = bh >> 4, h = bh & 15;
  const int tid = threadIdx.x;
  const int wave = tid >> 6, lane = tid & 63;
  const int quad = lane >> 4, l16 = lane & 15;
  const int qbase = (logical & 15) * 128 + wave * 32;

  const u16* qp = qg + (size_t)bh * Sn * DHn;
  const u16* kp = kg + (size_t)bh * Sn * DHn;
  const u16* vp = vg + (size_t)bh * DHn * Sn;   // [DH][S]

  __shared__ u16 Ks[2][64 * 64];    // 16 KB
  __shared__ u16 Vs[2][64 * 64];    // 16 KB

  const int srow8 = lane >> 3;
  const int gchunk = (lane & 7) ^ srow8;
  const int sw = l16 & 7;
  const int rbase = wave * 16;

  short8 bq[2][2];
#pragma unroll
  for (int g2 = 0; g2 < 2; g2++) {
    bq[g2][0] = *(const short8*)&qp[(size_t)(qbase + g2 * 16 + l16) * DHn + quad * 8];
    bq[g2][1] = *(const short8*)&qp[(size_t)(qbase + g2 * 16 + l16) * DHn + 32 + quad * 8];
  }

  f32x4 octx[2][4];
#pragma unroll
  for (int g2 = 0; g2 < 2; g2++)
#pragma unroll
    for (int j = 0; j < 4; j++) octx[g2][j] = (f32x4){0.f, 0.f, 0.f, 0.f};
  f32x4 octl[2];
  octl[0] = (f32x4){0.f, 0.f, 0.f, 0.f};
  octl[1] = (f32x4){0.f, 0.f, 0.f, 0.f};
  const short4v vones = {(short)0x3F80, (short)0x3F80, (short)0x3F80, (short)0x3F80};

  // prologue: stage K,V tile 0 (async, 16 rows/wave each)
  async16(&kp[(size_t)(rbase + srow8) * DHn + gchunk * 8], &Ks[0][rbase * 64]);
  async16(&kp[(size_t)(rbase + 8 + srow8) * DHn + gchunk * 8], &Ks[0][(rbase + 8) * 64]);
  async16(&vp[(size_t)(rbase + srow8) * Sn + gchunk * 8], &Vs[0][rbase * 64]);
  async16(&vp[(size_t)(rbase + 8 + srow8) * Sn + gchunk * 8], &Vs[0][(rbase + 8) * 64]);
  __syncthreads();

  for (int kt = 0; kt < Sn / 64; ++kt) {
    const int cur = kt & 1, nxt = cur ^ 1;
    if (kt + 1 < Sn / 64) {
      const int key1 = (kt + 1) * 64;
      async16(&kp[(size_t)(key1 + rbase + srow8) * DHn + gchunk * 8], &Ks[nxt][rbase * 64]);
      async16(&kp[(size_t)(key1 + rbase + 8 + srow8) * DHn + gchunk * 8], &Ks[nxt][(rbase + 8) * 64]);
      async16(&vp[(size_t)(rbase + srow8) * Sn + key1 + gchunk * 8], &Vs[nxt][rbase * 64]);
      async16(&vp[(size_t)(rbase + 8 + srow8) * Sn + key1 + gchunk * 8], &Vs[nxt][(rbase + 8) * 64]);
    }

    // QK^T + exp2 + pack, 32 q-rows x 64 keys
    short4v ap[2][4];
#pragma unroll
    for (int g = 0; g < 4; g++) {
      short8 ka0 = *(const short8*)&Ks[cur][(g * 16 + l16) * 64 + (quad ^ sw) * 8];
      short8 ka1 = *(const short8*)&Ks[cur][(g * 16 + l16) * 64 + ((quad + 4) ^ sw) * 8];
#pragma unroll
      for (int g2 = 0; g2 < 2; g2++) {
        f32x4 sc = (f32x4){0.f, 0.f, 0.f, 0.f};
        sc = __builtin_amdgcn_mfma_f32_16x16x32_bf16(ka0, bq[g2][0], sc, 0, 0, 0);
        sc = __builtin_amdgcn_mfma_f32_16x16x32_bf16(ka1, bq[g2][1], sc, 0, 0, 0);
        float pp[4];
#pragma unroll
        for (int r = 0; r < 4; r++) pp[r] = __builtin_amdgcn_exp2f(sc[r]);
        ap[g2][g] = __builtin_bit_cast(short4v, (uint2v){pk2(pp[0], pp[1]), pk2(pp[2], pp[3])});
      }
    }

    // lr via ones-B MFMA + PV
    __builtin_amdgcn_s_setprio(1);
#pragma unroll
    for (int g = 0; g < 4; g++) {
      octl[0] = __builtin_amdgcn_mfma_f32_16x16x16bf16_1k(ap[0][g], vones, octl[0], 0, 0, 0);
      octl[1] = __builtin_amdgcn_mfma_f32_16x16x16bf16_1k(ap[1][g], vones, octl[1], 0, 0, 0);
    }
#pragma unroll
    for (int j = 0; j < 4; j++) {
#pragma unroll
      for (int g = 0; g < 4; g++) {
        short4v vb = *(const short4v*)&Vs[cur][(j * 16 + l16) * 64 +
            ((g * 2 + (quad >> 1)) ^ sw) * 8 + (quad & 1) * 4];
        octx[0][j] = __builtin_amdgcn_mfma_f32_16x16x16bf16_1k(ap[0][g], vb, octx[0][j], 0, 0, 0);
        octx[1][j] = __builtin_amdgcn_mfma_f32_16x16x16bf16_1k(ap[1][g], vb, octx[1][j], 0, 0, 0);
      }
    }
    __builtin_amdgcn_s_setprio(0);
    __syncthreads();                  // drains next-tile DMA; Vs/Ks[cur] reads done
  }

  // octl[g2][r] = lr for q-row (g2*16 + quad*4 + r), identical across l16
  float rl[2][4];
#pragma unroll
  for (int g2 = 0; g2 < 2; g2++)
#pragma unroll
    for (int r = 0; r < 4; r++)
      rl[g2][r] = 1.0f / octl[g2][r];

#pragma unroll
  for (int g2 = 0; g2 < 2; g2++)
#pragma unroll
    for (int j = 0; j < 4; j++) {
      const int n = h * DHn + j * 16 + l16;
#pragma unroll
      for (int r = 0; r < 4; r++) {
        const int s = qbase + g2 * 16 + quad * 4 + r;
        ctx[(size_t)(b * Sn + s) * Dn + n] = f2bf(octx[g2][j][r] * rl[g2][r]);
      }
    }
}

// ---------------- output projection GEMM: 512 thr / 8 waves, swapped epilogue ----------------
__global__ __launch_bounds__(512) void k_gemm_out(
    const u16* __restrict__ A, const u16* __restrict__ WoT,
    const float* __restrict__ bo, float* __restrict__ out) {
  const int tile_m = blockIdx.x * 128;
  const int tile_n = blockIdx.y * 128;
  const int K = Dn;

  __shared__ u16 As[128 * 64];
  __shared__ u16 Bs[128 * 64];

  const int tid = threadIdx.x;
  const int lane = tid & 63;
  const int wave = tid >> 6;
  const int wm = wave & 3, wn = wave >> 2;
  const int quad = lane >> 4, l16 = lane & 15;
  const int srow8 = lane >> 3;
  const int gchunk = (lane & 7) ^ srow8;
  const int sw = l16 & 7;

  f32x4 acc[2][4];
#pragma unroll
  for (int i = 0; i < 2; i++)
#pragma unroll
    for (int j = 0; j < 4; j++) acc[i][j] = (f32x4){0.f, 0.f, 0.f, 0.f};

  for (int k0 = 0; k0 < K; k0 += 64) {
    const int rb = wave * 16;
    async16(&A[(size_t)(tile_m + rb + srow8) * K + k0 + gchunk * 8], &As[rb * 64]);
    async16(&A[(size_t)(tile_m + rb + 8 + srow8) * K + k0 + gchunk * 8], &As[(rb + 8) * 64]);
    async16(&WoT[(size_t)(tile_n + rb + srow8) * K + k0 + gchunk * 8], &Bs[rb * 64]);
    async16(&WoT[(size_t)(tile_n + rb + 8 + srow8) * K + k0 + gchunk * 8], &Bs[(rb + 8) * 64]);
    __syncthreads();
#pragma unroll
    for (int ks = 0; ks < 2; ++ks) {
      short8 a[2], b[4];
#pragma unroll
      for (int i = 0; i < 2; i++)
        a[i] = *(const short8*)&As[(wm * 32 + i * 16 + l16) * 64 + ((ks * 4 + quad) ^ sw) * 8];
#pragma unroll
      for (int j = 0; j < 4; j++)
        b[j] = *(const short8*)&Bs[(wn * 64 + j * 16 + l16) * 64 + ((ks * 4 + quad) ^ sw) * 8];
#pragma unroll
      for (int i = 0; i < 2; i++)
#pragma unroll
        for (int j = 0; j < 4; j++)
          acc[i][j] = __builtin_amdgcn_mfma_f32_16x16x32_bf16(b[j], a[i], acc[i][j], 0, 0, 0);
    }
    __syncthreads();
  }

#pragma unroll
  for (int i = 0; i < 2; i++) {
    const int s = tile_m + wm * 32 + i * 16 + l16;
#pragma unroll
    for (int j = 0; j < 4; j++) {
      const int nb = tile_n + wn * 64 + j * 16 + quad * 4;
      const float4 b4 = *(const float4*)&bo[nb];
      float4 o;
      o.x = acc[i][j][0] + b4.x;
      o.y = acc[i][j][1] + b4.y;
      o.z = acc[i][j][2] + b4.z;
      o.w = acc[i][j][3] + b4.w;
      *(float4*)&out[(size_t)s * Dn + nb] = o;
    }
  }
}

extern "C" void kernel_launch(void* const* d_in, const int* in_sizes, int n_in,
                              void* d_out, int out_size, void* d_ws, size_t ws_size,
                              hipStream_t stream) {
  const float* x  = (const float*)d_in[0];
  const float* Wq = (const float*)d_in[1];
  const float* bq = (const float*)d_in[2];
  const float* Wk = (const float*)d_in[3];
  const float* bk = (const float*)d_in[4];
  const float* Wv = (const float*)d_in[5];
  const float* bv = (const float*)d_in[6];
  const float* Wo = (const float*)d_in[7];
  const float* bo = (const float*)d_in[8];
  float* out = (float*)d_out;

  // workspace carve-up (ctx aliases xb: xb dead after k_gemm_qkv) — ~75.5 MB
  char* ws = (char*)d_ws;
  u16* xb  = (u16*)ws;  ws += (size_t)Mn * Dn * 2;
  u16* WqT = (u16*)ws;  ws += (size_t)Dn * Dn * 2;
  u16* WkT = (u16*)ws;  ws += (size_t)Dn * Dn * 2;
  u16* WvT = (u16*)ws;  ws += (size_t)Dn * Dn * 2;
  u16* WoT = (u16*)ws;  ws += (size_t)Dn * Dn * 2;
  u16* qb  = (u16*)ws;  ws += (size_t)Mn * Dn * 2;
  u16* kb  = (u16*)ws;  ws += (size_t)Mn * Dn * 2;
  u16* vtb = (u16*)ws;  ws += (size_t)Mn * Dn * 2;
  u16* ctx = xb;        // alias

  k_convert_x<<<(Mn * Dn / 4) / 256, 256, 0, stream>>>((const float4*)x, (ushort4*)xb, Mn * Dn / 4);
  k_convert_w<<<1024, 256, 0, stream>>>(Wq, Wk, Wv, Wo, WqT, WkT, WvT, WoT);

  dim3 g1(Mn / 128, Dn / 128, 3);
  k_gemm_qkv<<<g1, 512, 0, stream>>>(xb, WqT, WkT, WvT, bq, bk, bv, qb, kb, vtb);

  k_attn<<<(Sn / 128) * Bn * Hn, 256, 0, stream>>>(qb, kb, vtb, ctx);

  dim3 g3(Mn / 128, Dn / 128);
  k_gemm_out<<<g3, 512, 0, stream>>>(ctx, WoT, bo, out);
}

// Round 5
// 282.097 us; speedup vs baseline: 2.9819x; 1.0806x over previous
//
#include <hip/hip_runtime.h>

// MHA: B=4 S=2048 D=1024 H=16 DH=64. Full bf16-MFMA pipeline (fp32 accum).

#define Bn  4
#define Sn  2048
#define Dn  1024
#define Hn  16
#define DHn 64
#define Mn  (Bn*Sn)          // 8192 rows
#define LDKV 72              // attn V LDS row stride (ushorts)

typedef unsigned short u16;
typedef __attribute__((ext_vector_type(8))) short short8;   // 8 x bf16 (4 VGPRs)
typedef __attribute__((ext_vector_type(4))) short short4v;  // 4 x bf16 (2 VGPRs)
typedef __attribute__((ext_vector_type(4))) float f32x4;    // MFMA C/D frag
typedef __attribute__((ext_vector_type(2))) unsigned int uint2v;

__device__ __forceinline__ u16 f2bf(float f) {
  unsigned u = __float_as_uint(f);
  return (u16)((u + 0x7FFFu + ((u >> 16) & 1u)) >> 16);   // RNE
}

// async 16B/lane global->LDS DMA; lds dest = wave-uniform base + lane*16
__device__ __forceinline__ void async16(const void* g, void* l) {
  __builtin_amdgcn_global_load_lds(
      (const __attribute__((address_space(1))) void*)g,
      (__attribute__((address_space(3))) void*)l, 16, 0, 0);
}

// pack 2 fp32 -> 2 bf16 (truncation) in one v_perm_b32
__device__ __forceinline__ unsigned pk2(float a, float b) {
  return __builtin_amdgcn_perm(__float_as_uint(b), __float_as_uint(a), 0x07060302u);
}

// ---------------- convert: x (f32) -> xb (bf16) ----------------
__global__ __launch_bounds__(256) void k_convert_x(
    const float4* __restrict__ x, ushort4* __restrict__ xb, int n4) {
  int i = blockIdx.x * 256 + threadIdx.x;
  if (i < n4) {
    float4 f = x[i];
    ushort4 o;
    o.x = f2bf(f.x); o.y = f2bf(f.y); o.z = f2bf(f.z); o.w = f2bf(f.w);
    xb[i] = o;
  }
}

// ---- convert+transpose weights to [N][K] bf16 via LDS 64x64 tiles ----
__global__ __launch_bounds__(256) void k_convert_w(
    const float* __restrict__ Wq, const float* __restrict__ Wk,
    const float* __restrict__ Wv, const float* __restrict__ Wo,
    u16* __restrict__ WqT, u16* __restrict__ WkT,
    u16* __restrict__ WvT, u16* __restrict__ WoT) {
  __shared__ float t[64][65];
  const int bid = blockIdx.x;          // 0..1023
  const int wsel = bid >> 8;           // 0..3
  const int idx = bid & 255;
  const int tid = threadIdx.x;
  const int c = tid & 63;
  const int r4 = tid >> 6;             // 0..3

  if (wsel < 3) {
    const float* W = (wsel == 0) ? Wq : (wsel == 1) ? Wk : Wv;
    u16* T = (wsel == 0) ? WqT : (wsel == 1) ? WkT : WvT;
    const int h = idx >> 4;
    const int d0 = (idx & 15) * 64;
    const float* src = W + (size_t)h * (Dn * DHn) + (size_t)d0 * DHn;
#pragma unroll
    for (int r = 0; r < 16; r++) {
      int row = r * 4 + r4;
      t[row][c] = src[row * DHn + c];
    }
    __syncthreads();
    u16* dst = T + (size_t)(h * 64) * Dn + d0;
#pragma unroll
    for (int r = 0; r < 16; r++) {
      int erow = r * 4 + r4;
      dst[(size_t)erow * Dn + c] = f2bf(t[c][erow]);
    }
  } else {
    const int n0 = (idx >> 4) * 64;
    const int d0 = (idx & 15) * 64;
#pragma unroll
    for (int r = 0; r < 16; r++) {
      int row = r * 4 + r4;
      t[row][c] = Wo[(size_t)(d0 + row) * Dn + n0 + c];
    }
    __syncthreads();
#pragma unroll
    for (int r = 0; r < 16; r++) {
      int nrow = r * 4 + r4;
      WoT[(size_t)(n0 + nrow) * Dn + d0 + c] = f2bf(t[c][nrow]);
    }
  }
}

// ---------------- QKV projection GEMM body: 512 thr / 8 waves, 128x128 tile ----------------
// SWAP=1 (q,k): D computed transposed (mfma(b,a)) -> lane holds 4 contiguous e
//   -> one ushort4 store per frag, layout [B,H,S,DH].
// SWAP=0 (v): natural order -> 4 contiguous s per lane -> ushort4, [B,H,DH,S].
template<int SWAP>
__device__ __forceinline__ void qkv_body(
    u16* As, u16* Bs, const u16* __restrict__ A, const u16* __restrict__ BT,
    const float* __restrict__ bias, u16* __restrict__ dst, float scale,
    int tile_m, int tile_n) {
  const int K = Dn;
  const int tid = threadIdx.x;
  const int lane = tid & 63;
  const int wave = tid >> 6;                    // 0..7
  const int wm = wave & 3, wn = wave >> 2;
  const int quad = lane >> 4, l16 = lane & 15;
  const int srow8 = lane >> 3;
  const int gchunk = (lane & 7) ^ srow8;
  const int sw = l16 & 7;

  f32x4 acc[2][4];
#pragma unroll
  for (int i = 0; i < 2; i++)
#pragma unroll
    for (int j = 0; j < 4; j++) acc[i][j] = (f32x4){0.f, 0.f, 0.f, 0.f};

  for (int k0 = 0; k0 < K; k0 += 64) {
    const int rb = wave * 16;
    async16(&A[(size_t)(tile_m + rb + srow8) * K + k0 + gchunk * 8], &As[rb * 64]);
    async16(&A[(size_t)(tile_m + rb + 8 + srow8) * K + k0 + gchunk * 8], &As[(rb + 8) * 64]);
    async16(&BT[(size_t)(tile_n + rb + srow8) * K + k0 + gchunk * 8], &Bs[rb * 64]);
    async16(&BT[(size_t)(tile_n + rb + 8 + srow8) * K + k0 + gchunk * 8], &Bs[(rb + 8) * 64]);
    __syncthreads();
#pragma unroll
    for (int ks = 0; ks < 2; ++ks) {
      short8 a[2], b[4];
#pragma unroll
      for (int i = 0; i < 2; i++)
        a[i] = *(const short8*)&As[(wm * 32 + i * 16 + l16) * 64 + ((ks * 4 + quad) ^ sw) * 8];
#pragma unroll
      for (int j = 0; j < 4; j++)
        b[j] = *(const short8*)&Bs[(wn * 64 + j * 16 + l16) * 64 + ((ks * 4 + quad) ^ sw) * 8];
#pragma unroll
      for (int i = 0; i < 2; i++)
#pragma unroll
        for (int j = 0; j < 4; j++)
          acc[i][j] = SWAP
              ? __builtin_amdgcn_mfma_f32_16x16x32_bf16(b[j], a[i], acc[i][j], 0, 0, 0)
              : __builtin_amdgcn_mfma_f32_16x16x32_bf16(a[i], b[j], acc[i][j], 0, 0, 0);
    }
    __syncthreads();
  }

  if (SWAP) {
    // D^T: row = n (quad*4+r within j-block), col = s (l16)
#pragma unroll
    for (int i = 0; i < 2; i++) {
      const int s = tile_m + wm * 32 + i * 16 + l16;
      const int bb = s >> 11, sl = s & 2047;
#pragma unroll
      for (int j = 0; j < 4; j++) {
        const int nb = tile_n + wn * 64 + j * 16 + quad * 4;
        const float4 b4 = *(const float4*)&bias[nb];
        const int h = nb >> 6, e0 = nb & 63;
        ushort4 o;
        o.x = f2bf((acc[i][j][0] + b4.x) * scale);
        o.y = f2bf((acc[i][j][1] + b4.y) * scale);
        o.z = f2bf((acc[i][j][2] + b4.z) * scale);
        o.w = f2bf((acc[i][j][3] + b4.w) * scale);
        *(ushort4*)&dst[((size_t)(bb * Hn + h) * Sn + sl) * DHn + e0] = o;
      }
    }
  } else {
    // natural: row = s (quad*4+r), col = n (l16); v layout [B,H,DH,S]
#pragma unroll
    for (int i = 0; i < 2; i++) {
      const int s0 = tile_m + wm * 32 + i * 16 + quad * 4;
      const int bb = s0 >> 11, sl = s0 & 2047;
#pragma unroll
      for (int j = 0; j < 4; j++) {
        const int n = tile_n + wn * 64 + j * 16 + l16;
        const int h = n >> 6, e = n & 63;
        const float bn = bias[n];
        ushort4 o;
        o.x = f2bf(acc[i][j][0] + bn);
        o.y = f2bf(acc[i][j][1] + bn);
        o.z = f2bf(acc[i][j][2] + bn);
        o.w = f2bf(acc[i][j][3] + bn);
        *(ushort4*)&dst[((size_t)(bb * Hn + h) * DHn + e) * Sn + sl] = o;
      }
    }
  }
}

// single dispatch, z = 0(q) / 1(k) / 2(v); both epilogue styles preserved
__global__ __launch_bounds__(512) void k_gemm_qkv(
    const u16* __restrict__ A, const u16* __restrict__ WqT,
    const u16* __restrict__ WkT, const u16* __restrict__ WvT,
    const float* __restrict__ bq, const float* __restrict__ bk,
    const float* __restrict__ bv, u16* __restrict__ qb,
    u16* __restrict__ kb, u16* __restrict__ vtb) {
  __shared__ u16 As[128 * 64];
  __shared__ u16 Bs[128 * 64];
  const int tile_m = blockIdx.x * 128;
  const int tile_n = blockIdx.y * 128;
  const int z = blockIdx.z;
  if (z == 2) {
    qkv_body<0>(As, Bs, A, WvT, bv, vtb, 1.0f, tile_m, tile_n);
  } else if (z == 1) {
    qkv_body<1>(As, Bs, A, WkT, bk, kb, 1.0f, tile_m, tile_n);
  } else {
    qkv_body<1>(As, Bs, A, WqT, bq, qb, 0.18033688011112042f, tile_m, tile_n);
  }
}

// ---------------- flash attention (R0 structure + XCD-local block decode) ----------------
// 4 waves x 32 q-rows, 64 keys/tile. 1-D grid of 1024; p&7 selects the XCD
// (default round-robin dispatch), p>>3 walks blocks within the XCD so the 16
// q-tiles of each bh share one XCD's L2 (8 bh-streams x 512KB = 4MB per L2).
// R4-verified: FETCH_SIZE 139MB -> 24.6MB with this decode.
__global__ __launch_bounds__(256) void k_attn(
    const u16* __restrict__ qg, const u16* __restrict__ kg,
    const u16* __restrict__ vg, u16* __restrict__ ctx) {
  const int p = blockIdx.x;                         // 0..1023
  const int logical = (p & 7) * 128 + (p >> 3);     // same-bh blocks -> same XCD
  const int bh = logical >> 4;
  const int b = bh >> 4, h = bh & 15;
  const int tid = threadIdx.x;
  const int wave = tid >> 6, lane = tid & 63;
  const int quad = lane >> 4, l16 = lane & 15;
  const int qbase = (logical & 15) * 128 + wave * 32;

  const u16* qp = qg + (size_t)bh * Sn * DHn;
  const u16* kp = kg + (size_t)bh * Sn * DHn;
  const u16* vp = vg + (size_t)bh * DHn * Sn;   // [DH][S]

  __shared__ u16 Ks[2][64 * 64];
  __shared__ u16 Vs[2][64 * LDKV];

  const int srow8 = lane >> 3;
  const int gchunk = (lane & 7) ^ srow8;
  const int sw = l16 & 7;

  const int vrow = tid >> 3;
  const int vc = tid & 7;

  short8 bq[2][2];
#pragma unroll
  for (int g2 = 0; g2 < 2; g2++) {
    bq[g2][0] = *(const short8*)&qp[(size_t)(qbase + g2 * 16 + l16) * DHn + quad * 8];
    bq[g2][1] = *(const short8*)&qp[(size_t)(qbase + g2 * 16 + l16) * DHn + 32 + quad * 8];
  }

  f32x4 octx[2][4];
#pragma unroll
  for (int g2 = 0; g2 < 2; g2++)
#pragma unroll
    for (int j = 0; j < 4; j++) octx[g2][j] = (f32x4){0.f, 0.f, 0.f, 0.f};
  float lr[2] = {0.f, 0.f};

  {
    const int rbase = wave * 16;
    async16(&kp[(size_t)(rbase + srow8) * DHn + gchunk * 8], &Ks[0][rbase * 64]);
    async16(&kp[(size_t)(rbase + 8 + srow8) * DHn + gchunk * 8], &Ks[0][(rbase + 8) * 64]);
    uint4 vv0 = *(const uint4*)&vp[(size_t)vrow * Sn + vc * 8];
    uint4 vv1 = *(const uint4*)&vp[(size_t)(32 + vrow) * Sn + vc * 8];
    *(uint4*)&Vs[0][vrow * LDKV + vc * 8] = vv0;
    *(uint4*)&Vs[0][(32 + vrow) * LDKV + vc * 8] = vv1;
  }
  __syncthreads();

  uint4 vv0, vv1;
  for (int kt = 0; kt < Sn / 64; ++kt) {
    const int cur = kt & 1, nxt = cur ^ 1;
    const bool more = (kt + 1 < Sn / 64);
    if (more) {
      const int key1 = (kt + 1) * 64;
      const int rbase = wave * 16;
      async16(&kp[(size_t)(key1 + rbase + srow8) * DHn + gchunk * 8], &Ks[nxt][rbase * 64]);
      async16(&kp[(size_t)(key1 + rbase + 8 + srow8) * DHn + gchunk * 8], &Ks[nxt][(rbase + 8) * 64]);
      vv0 = *(const uint4*)&vp[(size_t)vrow * Sn + key1 + vc * 8];
      vv1 = *(const uint4*)&vp[(size_t)(32 + vrow) * Sn + key1 + vc * 8];
    }

    short4v ap[2][4];
#pragma unroll
    for (int g = 0; g < 4; g++) {
      short8 ka0 = *(const short8*)&Ks[cur][(g * 16 + l16) * 64 + (quad ^ sw) * 8];
      short8 ka1 = *(const short8*)&Ks[cur][(g * 16 + l16) * 64 + ((quad + 4) ^ sw) * 8];
#pragma unroll
      for (int g2 = 0; g2 < 2; g2++) {
        f32x4 sc = (f32x4){0.f, 0.f, 0.f, 0.f};
        sc = __builtin_amdgcn_mfma_f32_16x16x32_bf16(ka0, bq[g2][0], sc, 0, 0, 0);
        sc = __builtin_amdgcn_mfma_f32_16x16x32_bf16(ka1, bq[g2][1], sc, 0, 0, 0);
        float p4[4];
#pragma unroll
        for (int r = 0; r < 4; r++) p4[r] = __builtin_amdgcn_exp2f(sc[r]);
        lr[g2] += (p4[0] + p4[1]) + (p4[2] + p4[3]);
        ap[g2][g] = __builtin_bit_cast(short4v,
            (uint2v){pk2(p4[0], p4[1]), pk2(p4[2], p4[3])});
      }
    }

#pragma unroll
    for (int j = 0; j < 4; j++) {
#pragma unroll
      for (int g = 0; g < 4; g++) {
        short4v vb = *(const short4v*)&Vs[cur][(j * 16 + l16) * LDKV + g * 16 + quad * 4];
        octx[0][j] = __builtin_amdgcn_mfma_f32_16x16x16bf16_1k(ap[0][g], vb, octx[0][j], 0, 0, 0);
        octx[1][j] = __builtin_amdgcn_mfma_f32_16x16x16bf16_1k(ap[1][g], vb, octx[1][j], 0, 0, 0);
      }
    }

    if (more) {
      *(uint4*)&Vs[nxt][vrow * LDKV + vc * 8] = vv0;
      *(uint4*)&Vs[nxt][(32 + vrow) * LDKV + vc * 8] = vv1;
    }
    __syncthreads();
  }

#pragma unroll
  for (int g2 = 0; g2 < 2; g2++) {
    lr[g2] += __shfl_xor(lr[g2], 16, 64);
    lr[g2] += __shfl_xor(lr[g2], 32, 64);
  }
  float rl[2][4];
#pragma unroll
  for (int g2 = 0; g2 < 2; g2++)
#pragma unroll
    for (int r = 0; r < 4; r++)
      rl[g2][r] = 1.0f / __shfl(lr[g2], quad * 4 + r, 64);

#pragma unroll
  for (int g2 = 0; g2 < 2; g2++)
#pragma unroll
    for (int j = 0; j < 4; j++) {
      const int n = h * DHn + j * 16 + l16;
#pragma unroll
      for (int r = 0; r < 4; r++) {
        const int s = qbase + g2 * 16 + quad * 4 + r;
        ctx[(size_t)(b * Sn + s) * Dn + n] = f2bf(octx[g2][j][r] * rl[g2][r]);
      }
    }
}

// ---------------- output projection GEMM: 512 thr / 8 waves, swapped epilogue ----------------
__global__ __launch_bounds__(512) void k_gemm_out(
    const u16* __restrict__ A, const u16* __restrict__ WoT,
    const float* __restrict__ bo, float* __restrict__ out) {
  const int tile_m = blockIdx.x * 128;
  const int tile_n = blockIdx.y * 128;
  const int K = Dn;

  __shared__ u16 As[128 * 64];
  __shared__ u16 Bs[128 * 64];

  const int tid = threadIdx.x;
  const int lane = tid & 63;
  const int wave = tid >> 6;
  const int wm = wave & 3, wn = wave >> 2;
  const int quad = lane >> 4, l16 = lane & 15;
  const int srow8 = lane >> 3;
  const int gchunk = (lane & 7) ^ srow8;
  const int sw = l16 & 7;

  f32x4 acc[2][4];
#pragma unroll
  for (int i = 0; i < 2; i++)
#pragma unroll
    for (int j = 0; j < 4; j++) acc[i][j] = (f32x4){0.f, 0.f, 0.f, 0.f};

  for (int k0 = 0; k0 < K; k0 += 64) {
    const int rb = wave * 16;
    async16(&A[(size_t)(tile_m + rb + srow8) * K + k0 + gchunk * 8], &As[rb * 64]);
    async16(&A[(size_t)(tile_m + rb + 8 + srow8) * K + k0 + gchunk * 8], &As[(rb + 8) * 64]);
    async16(&WoT[(size_t)(tile_n + rb + srow8) * K + k0 + gchunk * 8], &Bs[rb * 64]);
    async16(&WoT[(size_t)(tile_n + rb + 8 + srow8) * K + k0 + gchunk * 8], &Bs[(rb + 8) * 64]);
    __syncthreads();
#pragma unroll
    for (int ks = 0; ks < 2; ++ks) {
      short8 a[2], b[4];
#pragma unroll
      for (int i = 0; i < 2; i++)
        a[i] = *(const short8*)&As[(wm * 32 + i * 16 + l16) * 64 + ((ks * 4 + quad) ^ sw) * 8];
#pragma unroll
      for (int j = 0; j < 4; j++)
        b[j] = *(const short8*)&Bs[(wn * 64 + j * 16 + l16) * 64 + ((ks * 4 + quad) ^ sw) * 8];
#pragma unroll
      for (int i = 0; i < 2; i++)
#pragma unroll
        for (int j = 0; j < 4; j++)
          acc[i][j] = __builtin_amdgcn_mfma_f32_16x16x32_bf16(b[j], a[i], acc[i][j], 0, 0, 0);
    }
    __syncthreads();
  }

#pragma unroll
  for (int i = 0; i < 2; i++) {
    const int s = tile_m + wm * 32 + i * 16 + l16;
#pragma unroll
    for (int j = 0; j < 4; j++) {
      const int nb = tile_n + wn * 64 + j * 16 + quad * 4;
      const float4 b4 = *(const float4*)&bo[nb];
      float4 o;
      o.x = acc[i][j][0] + b4.x;
      o.y = acc[i][j][1] + b4.y;
      o.z = acc[i][j][2] + b4.z;
      o.w = acc[i][j][3] + b4.w;
      *(float4*)&out[(size_t)s * Dn + nb] = o;
    }
  }
}

extern "C" void kernel_launch(void* const* d_in, const int* in_sizes, int n_in,
                              void* d_out, int out_size, void* d_ws, size_t ws_size,
                              hipStream_t stream) {
  const float* x  = (const float*)d_in[0];
  const float* Wq = (const float*)d_in[1];
  const float* bq = (const float*)d_in[2];
  const float* Wk = (const float*)d_in[3];
  const float* bk = (const float*)d_in[4];
  const float* Wv = (const float*)d_in[5];
  const float* bv = (const float*)d_in[6];
  const float* Wo = (const float*)d_in[7];
  const float* bo = (const float*)d_in[8];
  float* out = (float*)d_out;

  // workspace carve-up (ctx aliases xb: xb dead after k_gemm_qkv) — ~75.5 MB
  char* ws = (char*)d_ws;
  u16* xb  = (u16*)ws;  ws += (size_t)Mn * Dn * 2;
  u16* WqT = (u16*)ws;  ws += (size_t)Dn * Dn * 2;
  u16* WkT = (u16*)ws;  ws += (size_t)Dn * Dn * 2;
  u16* WvT = (u16*)ws;  ws += (size_t)Dn * Dn * 2;
  u16* WoT = (u16*)ws;  ws += (size_t)Dn * Dn * 2;
  u16* qb  = (u16*)ws;  ws += (size_t)Mn * Dn * 2;
  u16* kb  = (u16*)ws;  ws += (size_t)Mn * Dn * 2;
  u16* vtb = (u16*)ws;  ws += (size_t)Mn * Dn * 2;
  u16* ctx = xb;        // alias

  k_convert_x<<<(Mn * Dn / 4) / 256, 256, 0, stream>>>((const float4*)x, (ushort4*)xb, Mn * Dn / 4);
  k_convert_w<<<1024, 256, 0, stream>>>(Wq, Wk, Wv, Wo, WqT, WkT, WvT, WoT);

  dim3 g1(Mn / 128, Dn / 128, 3);
  k_gemm_qkv<<<g1, 512, 0, stream>>>(xb, WqT, WkT, WvT, bq, bk, bv, qb, kb, vtb);

  k_attn<<<(Sn / 128) * Bn * Hn, 256, 0, stream>>>(qb, kb, vtb, ctx);

  dim3 g3(Mn / 128, Dn / 128);
  k_gemm_out<<<g3, 512, 0, stream>>>(ctx, WoT, bo, out);
}

// Round 6
// 277.708 us; speedup vs baseline: 3.0291x; 1.0158x over previous
//
#include <hip/hip_runtime.h>

// MHA: B=4 S=2048 D=1024 H=16 DH=64. Full bf16-MFMA pipeline (fp32 accum).

#define Bn  4
#define Sn  2048
#define Dn  1024
#define Hn  16
#define DHn 64
#define Mn  (Bn*Sn)          // 8192 rows
#define LDKV 72              // attn V LDS row stride (ushorts)

typedef unsigned short u16;
typedef __attribute__((ext_vector_type(8))) short short8;   // 8 x bf16 (4 VGPRs)
typedef __attribute__((ext_vector_type(4))) short short4v;  // 4 x bf16 (2 VGPRs)
typedef __attribute__((ext_vector_type(4))) float f32x4;    // MFMA C/D frag
typedef __attribute__((ext_vector_type(2))) unsigned int uint2v;
typedef __attribute__((ext_vector_type(4))) unsigned int uint4v;

__device__ __forceinline__ u16 f2bf(float f) {
  unsigned u = __float_as_uint(f);
  return (u16)((u + 0x7FFFu + ((u >> 16) & 1u)) >> 16);   // RNE
}

// async 16B/lane global->LDS DMA; lds dest = wave-uniform base + lane*16
__device__ __forceinline__ void async16(const void* g, void* l) {
  __builtin_amdgcn_global_load_lds(
      (const __attribute__((address_space(1))) void*)g,
      (__attribute__((address_space(3))) void*)l, 16, 0, 0);
}

// pack 2 fp32 -> 2 bf16 (truncation) in one v_perm_b32
__device__ __forceinline__ unsigned pk2(float a, float b) {
  return __builtin_amdgcn_perm(__float_as_uint(b), __float_as_uint(a), 0x07060302u);
}

// ---------------- convert: x (f32) -> xb (bf16) ----------------
__global__ __launch_bounds__(256) void k_convert_x(
    const float4* __restrict__ x, ushort4* __restrict__ xb, int n4) {
  int i = blockIdx.x * 256 + threadIdx.x;
  if (i < n4) {
    float4 f = x[i];
    ushort4 o;
    o.x = f2bf(f.x); o.y = f2bf(f.y); o.z = f2bf(f.z); o.w = f2bf(f.w);
    xb[i] = o;
  }
}

// ---- convert+transpose weights to [N][K] bf16 via LDS 64x64 tiles ----
__global__ __launch_bounds__(256) void k_convert_w(
    const float* __restrict__ Wq, const float* __restrict__ Wk,
    const float* __restrict__ Wv, const float* __restrict__ Wo,
    u16* __restrict__ WqT, u16* __restrict__ WkT,
    u16* __restrict__ WvT, u16* __restrict__ WoT) {
  __shared__ float t[64][65];
  const int bid = blockIdx.x;          // 0..1023
  const int wsel = bid >> 8;           // 0..3
  const int idx = bid & 255;
  const int tid = threadIdx.x;
  const int c = tid & 63;
  const int r4 = tid >> 6;             // 0..3

  if (wsel < 3) {
    const float* W = (wsel == 0) ? Wq : (wsel == 1) ? Wk : Wv;
    u16* T = (wsel == 0) ? WqT : (wsel == 1) ? WkT : WvT;
    const int h = idx >> 4;
    const int d0 = (idx & 15) * 64;
    const float* src = W + (size_t)h * (Dn * DHn) + (size_t)d0 * DHn;
#pragma unroll
    for (int r = 0; r < 16; r++) {
      int row = r * 4 + r4;
      t[row][c] = src[row * DHn + c];
    }
    __syncthreads();
    u16* dst = T + (size_t)(h * 64) * Dn + d0;
#pragma unroll
    for (int r = 0; r < 16; r++) {
      int erow = r * 4 + r4;
      dst[(size_t)erow * Dn + c] = f2bf(t[c][erow]);
    }
  } else {
    const int n0 = (idx >> 4) * 64;
    const int d0 = (idx & 15) * 64;
#pragma unroll
    for (int r = 0; r < 16; r++) {
      int row = r * 4 + r4;
      t[row][c] = Wo[(size_t)(d0 + row) * Dn + n0 + c];
    }
    __syncthreads();
#pragma unroll
    for (int r = 0; r < 16; r++) {
      int nrow = r * 4 + r4;
      WoT[(size_t)(n0 + nrow) * Dn + d0 + c] = f2bf(t[c][nrow]);
    }
  }
}

// ---------------- QKV projection GEMM body: 512 thr / 8 waves, 128x128 tile ----------------
template<int SWAP>
__device__ __forceinline__ void qkv_body(
    u16* As, u16* Bs, const u16* __restrict__ A, const u16* __restrict__ BT,
    const float* __restrict__ bias, u16* __restrict__ dst, float scale,
    int tile_m, int tile_n) {
  const int K = Dn;
  const int tid = threadIdx.x;
  const int lane = tid & 63;
  const int wave = tid >> 6;                    // 0..7
  const int wm = wave & 3, wn = wave >> 2;
  const int quad = lane >> 4, l16 = lane & 15;
  const int srow8 = lane >> 3;
  const int gchunk = (lane & 7) ^ srow8;
  const int sw = l16 & 7;

  f32x4 acc[2][4];
#pragma unroll
  for (int i = 0; i < 2; i++)
#pragma unroll
    for (int j = 0; j < 4; j++) acc[i][j] = (f32x4){0.f, 0.f, 0.f, 0.f};

  for (int k0 = 0; k0 < K; k0 += 64) {
    const int rb = wave * 16;
    async16(&A[(size_t)(tile_m + rb + srow8) * K + k0 + gchunk * 8], &As[rb * 64]);
    async16(&A[(size_t)(tile_m + rb + 8 + srow8) * K + k0 + gchunk * 8], &As[(rb + 8) * 64]);
    async16(&BT[(size_t)(tile_n + rb + srow8) * K + k0 + gchunk * 8], &Bs[rb * 64]);
    async16(&BT[(size_t)(tile_n + rb + 8 + srow8) * K + k0 + gchunk * 8], &Bs[(rb + 8) * 64]);
    __syncthreads();
#pragma unroll
    for (int ks = 0; ks < 2; ++ks) {
      short8 a[2], b[4];
#pragma unroll
      for (int i = 0; i < 2; i++)
        a[i] = *(const short8*)&As[(wm * 32 + i * 16 + l16) * 64 + ((ks * 4 + quad) ^ sw) * 8];
#pragma unroll
      for (int j = 0; j < 4; j++)
        b[j] = *(const short8*)&Bs[(wn * 64 + j * 16 + l16) * 64 + ((ks * 4 + quad) ^ sw) * 8];
#pragma unroll
      for (int i = 0; i < 2; i++)
#pragma unroll
        for (int j = 0; j < 4; j++)
          acc[i][j] = SWAP
              ? __builtin_amdgcn_mfma_f32_16x16x32_bf16(b[j], a[i], acc[i][j], 0, 0, 0)
              : __builtin_amdgcn_mfma_f32_16x16x32_bf16(a[i], b[j], acc[i][j], 0, 0, 0);
    }
    __syncthreads();
  }

  if (SWAP) {
#pragma unroll
    for (int i = 0; i < 2; i++) {
      const int s = tile_m + wm * 32 + i * 16 + l16;
      const int bb = s >> 11, sl = s & 2047;
#pragma unroll
      for (int j = 0; j < 4; j++) {
        const int nb = tile_n + wn * 64 + j * 16 + quad * 4;
        const float4 b4 = *(const float4*)&bias[nb];
        const int h = nb >> 6, e0 = nb & 63;
        ushort4 o;
        o.x = f2bf((acc[i][j][0] + b4.x) * scale);
        o.y = f2bf((acc[i][j][1] + b4.y) * scale);
        o.z = f2bf((acc[i][j][2] + b4.z) * scale);
        o.w = f2bf((acc[i][j][3] + b4.w) * scale);
        *(ushort4*)&dst[((size_t)(bb * Hn + h) * Sn + sl) * DHn + e0] = o;
      }
    }
  } else {
#pragma unroll
    for (int i = 0; i < 2; i++) {
      const int s0 = tile_m + wm * 32 + i * 16 + quad * 4;
      const int bb = s0 >> 11, sl = s0 & 2047;
#pragma unroll
      for (int j = 0; j < 4; j++) {
        const int n = tile_n + wn * 64 + j * 16 + l16;
        const int h = n >> 6, e = n & 63;
        const float bn = bias[n];
        ushort4 o;
        o.x = f2bf(acc[i][j][0] + bn);
        o.y = f2bf(acc[i][j][1] + bn);
        o.z = f2bf(acc[i][j][2] + bn);
        o.w = f2bf(acc[i][j][3] + bn);
        *(ushort4*)&dst[((size_t)(bb * Hn + h) * DHn + e) * Sn + sl] = o;
      }
    }
  }
}

// single dispatch, z = 0(q) / 1(k) / 2(v); both epilogue styles preserved
__global__ __launch_bounds__(512) void k_gemm_qkv(
    const u16* __restrict__ A, const u16* __restrict__ WqT,
    const u16* __restrict__ WkT, const u16* __restrict__ WvT,
    const float* __restrict__ bq, const float* __restrict__ bk,
    const float* __restrict__ bv, u16* __restrict__ qb,
    u16* __restrict__ kb, u16* __restrict__ vtb) {
  __shared__ u16 As[128 * 64];
  __shared__ u16 Bs[128 * 64];
  const int tile_m = blockIdx.x * 128;
  const int tile_n = blockIdx.y * 128;
  const int z = blockIdx.z;
  if (z == 2) {
    qkv_body<0>(As, Bs, A, WvT, bv, vtb, 1.0f, tile_m, tile_n);
  } else if (z == 1) {
    qkv_body<1>(As, Bs, A, WkT, bk, kb, 1.0f, tile_m, tile_n);
  } else {
    qkv_body<1>(As, Bs, A, WqT, bq, qb, 0.18033688011112042f, tile_m, tile_n);
  }
}

// ---------------- flash attention (R0 structure + key-permuted K staging) ----------------
// 4 waves x 32 q-rows, 64 keys/tile, XCD-local block decode (R4-verified).
// K-tile LDS rows are staged in PERMUTED key order:
//   row rho -> key = (rho>>5)*32 + ((rho>>2)&3)*8 + ((rho>>4)&1)*4 + (rho&3)
// so QK group g = 2P+half leaves lane (quad,l16) holding keys
// P*32 + quad*8 + half*4 + {0..3} — the two halves concatenate IN-LANE into a
// 16x16x32 A-fragment (k = quad*8 + j). PV: 16x 16x16x32 MFMA (was 32x K=16)
// and 8x ds_read_b128 V (was 16x b64). exp2/lr are key-order-agnostic.
__global__ __launch_bounds__(256) void k_attn(
    const u16* __restrict__ qg, const u16* __restrict__ kg,
    const u16* __restrict__ vg, u16* __restrict__ ctx) {
  const int p = blockIdx.x;                         // 0..1023
  const int logical = (p & 7) * 128 + (p >> 3);     // same-bh blocks -> same XCD
  const int bh = logical >> 4;
  const int b = bh >> 4, h = bh & 15;
  const int tid = threadIdx.x;
  const int wave = tid >> 6, lane = tid & 63;
  const int quad = lane >> 4, l16 = lane & 15;
  const int qbase = (logical & 15) * 128 + wave * 32;

  const u16* qp = qg + (size_t)bh * Sn * DHn;
  const u16* kp = kg + (size_t)bh * Sn * DHn;
  const u16* vp = vg + (size_t)bh * DHn * Sn;   // [DH][S]

  __shared__ u16 Ks[2][64 * 64];
  __shared__ u16 Vs[2][64 * LDKV];

  const int srow8 = lane >> 3;
  const int gchunk = (lane & 7) ^ srow8;
  const int sw = l16 & 7;

  const int vrow = tid >> 3;
  const int vc = tid & 7;

  // permuted key indices for this lane's two staged K rows (loop-invariant)
  const int r0 = wave * 16 + srow8;
  const int r1 = r0 + 8;
  const int pk0 = ((r0 >> 5) << 5) | (((r0 >> 2) & 3) << 3) | ((r0 & 16) >> 2) | (r0 & 3);
  const int pk1 = ((r1 >> 5) << 5) | (((r1 >> 2) & 3) << 3) | ((r1 & 16) >> 2) | (r1 & 3);

  short8 bq[2][2];
#pragma unroll
  for (int g2 = 0; g2 < 2; g2++) {
    bq[g2][0] = *(const short8*)&qp[(size_t)(qbase + g2 * 16 + l16) * DHn + quad * 8];
    bq[g2][1] = *(const short8*)&qp[(size_t)(qbase + g2 * 16 + l16) * DHn + 32 + quad * 8];
  }

  f32x4 octx[2][4];
#pragma unroll
  for (int g2 = 0; g2 < 2; g2++)
#pragma unroll
    for (int j = 0; j < 4; j++) octx[g2][j] = (f32x4){0.f, 0.f, 0.f, 0.f};
  float lr[2] = {0.f, 0.f};

  {
    const int rbase = wave * 16;
    async16(&kp[(size_t)pk0 * DHn + gchunk * 8], &Ks[0][rbase * 64]);
    async16(&kp[(size_t)pk1 * DHn + gchunk * 8], &Ks[0][(rbase + 8) * 64]);
    uint4 vv0 = *(const uint4*)&vp[(size_t)vrow * Sn + vc * 8];
    uint4 vv1 = *(const uint4*)&vp[(size_t)(32 + vrow) * Sn + vc * 8];
    *(uint4*)&Vs[0][vrow * LDKV + vc * 8] = vv0;
    *(uint4*)&Vs[0][(32 + vrow) * LDKV + vc * 8] = vv1;
  }
  __syncthreads();

  uint4 vv0, vv1;
  for (int kt = 0; kt < Sn / 64; ++kt) {
    const int cur = kt & 1, nxt = cur ^ 1;
    const bool more = (kt + 1 < Sn / 64);
    if (more) {
      const int key1 = (kt + 1) * 64;
      const int rbase = wave * 16;
      async16(&kp[(size_t)(key1 + pk0) * DHn + gchunk * 8], &Ks[nxt][rbase * 64]);
      async16(&kp[(size_t)(key1 + pk1) * DHn + gchunk * 8], &Ks[nxt][(rbase + 8) * 64]);
      vv0 = *(const uint4*)&vp[(size_t)vrow * Sn + key1 + vc * 8];
      vv1 = *(const uint4*)&vp[(size_t)(32 + vrow) * Sn + key1 + vc * 8];
    }

    // QK^T + exp2 + pack; groups g = 2P + half fill apv[g2][P] halves in-lane
    uint4v apv[2][2];
#pragma unroll
    for (int g = 0; g < 4; g++) {
      short8 ka0 = *(const short8*)&Ks[cur][(g * 16 + l16) * 64 + (quad ^ sw) * 8];
      short8 ka1 = *(const short8*)&Ks[cur][(g * 16 + l16) * 64 + ((quad + 4) ^ sw) * 8];
#pragma unroll
      for (int g2 = 0; g2 < 2; g2++) {
        f32x4 sc = (f32x4){0.f, 0.f, 0.f, 0.f};
        sc = __builtin_amdgcn_mfma_f32_16x16x32_bf16(ka0, bq[g2][0], sc, 0, 0, 0);
        sc = __builtin_amdgcn_mfma_f32_16x16x32_bf16(ka1, bq[g2][1], sc, 0, 0, 0);
        float p4[4];
#pragma unroll
        for (int r = 0; r < 4; r++) p4[r] = __builtin_amdgcn_exp2f(sc[r]);
        lr[g2] += (p4[0] + p4[1]) + (p4[2] + p4[3]);
        apv[g2][g >> 1][(g & 1) * 2]     = pk2(p4[0], p4[1]);
        apv[g2][g >> 1][(g & 1) * 2 + 1] = pk2(p4[2], p4[3]);
      }
    }

    // PV: 16x 16x16x32 MFMA, A = in-lane P fragment, B = V short8 (b128)
#pragma unroll
    for (int j = 0; j < 4; j++) {
#pragma unroll
      for (int P = 0; P < 2; P++) {
        short8 vb = *(const short8*)&Vs[cur][(j * 16 + l16) * LDKV + P * 32 + quad * 8];
        octx[0][j] = __builtin_amdgcn_mfma_f32_16x16x32_bf16(
            __builtin_bit_cast(short8, apv[0][P]), vb, octx[0][j], 0, 0, 0);
        octx[1][j] = __builtin_amdgcn_mfma_f32_16x16x32_bf16(
            __builtin_bit_cast(short8, apv[1][P]), vb, octx[1][j], 0, 0, 0);
      }
    }

    if (more) {
      *(uint4*)&Vs[nxt][vrow * LDKV + vc * 8] = vv0;
      *(uint4*)&Vs[nxt][(32 + vrow) * LDKV + vc * 8] = vv1;
    }
    __syncthreads();
  }

#pragma unroll
  for (int g2 = 0; g2 < 2; g2++) {
    lr[g2] += __shfl_xor(lr[g2], 16, 64);
    lr[g2] += __shfl_xor(lr[g2], 32, 64);
  }
  float rl[2][4];
#pragma unroll
  for (int g2 = 0; g2 < 2; g2++)
#pragma unroll
    for (int r = 0; r < 4; r++)
      rl[g2][r] = 1.0f / __shfl(lr[g2], quad * 4 + r, 64);

#pragma unroll
  for (int g2 = 0; g2 < 2; g2++)
#pragma unroll
    for (int j = 0; j < 4; j++) {
      const int n = h * DHn + j * 16 + l16;
#pragma unroll
      for (int r = 0; r < 4; r++) {
        const int s = qbase + g2 * 16 + quad * 4 + r;
        ctx[(size_t)(b * Sn + s) * Dn + n] = f2bf(octx[g2][j][r] * rl[g2][r]);
      }
    }
}

// ---------------- output projection GEMM: 512 thr / 8 waves, swapped epilogue ----------------
__global__ __launch_bounds__(512) void k_gemm_out(
    const u16* __restrict__ A, const u16* __restrict__ WoT,
    const float* __restrict__ bo, float* __restrict__ out) {
  const int tile_m = blockIdx.x * 128;
  const int tile_n = blockIdx.y * 128;
  const int K = Dn;

  __shared__ u16 As[128 * 64];
  __shared__ u16 Bs[128 * 64];

  const int tid = threadIdx.x;
  const int lane = tid & 63;
  const int wave = tid >> 6;
  const int wm = wave & 3, wn = wave >> 2;
  const int quad = lane >> 4, l16 = lane & 15;
  const int srow8 = lane >> 3;
  const int gchunk = (lane & 7) ^ srow8;
  const int sw = l16 & 7;

  f32x4 acc[2][4];
#pragma unroll
  for (int i = 0; i < 2; i++)
#pragma unroll
    for (int j = 0; j < 4; j++) acc[i][j] = (f32x4){0.f, 0.f, 0.f, 0.f};

  for (int k0 = 0; k0 < K; k0 += 64) {
    const int rb = wave * 16;
    async16(&A[(size_t)(tile_m + rb + srow8) * K + k0 + gchunk * 8], &As[rb * 64]);
    async16(&A[(size_t)(tile_m + rb + 8 + srow8) * K + k0 + gchunk * 8], &As[(rb + 8) * 64]);
    async16(&WoT[(size_t)(tile_n + rb + srow8) * K + k0 + gchunk * 8], &Bs[rb * 64]);
    async16(&WoT[(size_t)(tile_n + rb + 8 + srow8) * K + k0 + gchunk * 8], &Bs[(rb + 8) * 64]);
    __syncthreads();
#pragma unroll
    for (int ks = 0; ks < 2; ++ks) {
      short8 a[2], b[4];
#pragma unroll
      for (int i = 0; i < 2; i++)
        a[i] = *(const short8*)&As[(wm * 32 + i * 16 + l16) * 64 + ((ks * 4 + quad) ^ sw) * 8];
#pragma unroll
      for (int j = 0; j < 4; j++)
        b[j] = *(const short8*)&Bs[(wn * 64 + j * 16 + l16) * 64 + ((ks * 4 + quad) ^ sw) * 8];
#pragma unroll
      for (int i = 0; i < 2; i++)
#pragma unroll
        for (int j = 0; j < 4; j++)
          acc[i][j] = __builtin_amdgcn_mfma_f32_16x16x32_bf16(b[j], a[i], acc[i][j], 0, 0, 0);
    }
    __syncthreads();
  }

#pragma unroll
  for (int i = 0; i < 2; i++) {
    const int s = tile_m + wm * 32 + i * 16 + l16;
#pragma unroll
    for (int j = 0; j < 4; j++) {
      const int nb = tile_n + wn * 64 + j * 16 + quad * 4;
      const float4 b4 = *(const float4*)&bo[nb];
      float4 o;
      o.x = acc[i][j][0] + b4.x;
      o.y = acc[i][j][1] + b4.y;
      o.z = acc[i][j][2] + b4.z;
      o.w = acc[i][j][3] + b4.w;
      *(float4*)&out[(size_t)s * Dn + nb] = o;
    }
  }
}

extern "C" void kernel_launch(void* const* d_in, const int* in_sizes, int n_in,
                              void* d_out, int out_size, void* d_ws, size_t ws_size,
                              hipStream_t stream) {
  const float* x  = (const float*)d_in[0];
  const float* Wq = (const float*)d_in[1];
  const float* bq = (const float*)d_in[2];
  const float* Wk = (const float*)d_in[3];
  const float* bk = (const float*)d_in[4];
  const float* Wv = (const float*)d_in[5];
  const float* bv = (const float*)d_in[6];
  const float* Wo = (const float*)d_in[7];
  const float* bo = (const float*)d_in[8];
  float* out = (float*)d_out;

  // workspace carve-up (ctx aliases xb: xb dead after k_gemm_qkv) — ~75.5 MB
  char* ws = (char*)d_ws;
  u16* xb  = (u16*)ws;  ws += (size_t)Mn * Dn * 2;
  u16* WqT = (u16*)ws;  ws += (size_t)Dn * Dn * 2;
  u16* WkT = (u16*)ws;  ws += (size_t)Dn * Dn * 2;
  u16* WvT = (u16*)ws;  ws += (size_t)Dn * Dn * 2;
  u16* WoT = (u16*)ws;  ws += (size_t)Dn * Dn * 2;
  u16* qb  = (u16*)ws;  ws += (size_t)Mn * Dn * 2;
  u16* kb  = (u16*)ws;  ws += (size_t)Mn * Dn * 2;
  u16* vtb = (u16*)ws;  ws += (size_t)Mn * Dn * 2;
  u16* ctx = xb;        // alias

  k_convert_x<<<(Mn * Dn / 4) / 256, 256, 0, stream>>>((const float4*)x, (ushort4*)xb, Mn * Dn / 4);
  k_convert_w<<<1024, 256, 0, stream>>>(Wq, Wk, Wv, Wo, WqT, WkT, WvT, WoT);

  dim3 g1(Mn / 128, Dn / 128, 3);
  k_gemm_qkv<<<g1, 512, 0, stream>>>(xb, WqT, WkT, WvT, bq, bk, bv, qb, kb, vtb);

  k_attn<<<(Sn / 128) * Bn * Hn, 256, 0, stream>>>(qb, kb, vtb, ctx);

  dim3 g3(Mn / 128, Dn / 128);
  k_gemm_out<<<g3, 512, 0, stream>>>(ctx, WoT, bo, out);
}